// Round 2
// baseline (809.114 us; speedup 1.0000x reference)
//
#include <hip/hip_runtime.h>
#include <hip/hip_bf16.h>

typedef __attribute__((ext_vector_type(8))) short short8x;  // 8 bf16 = 4 VGPR
typedef __attribute__((ext_vector_type(4))) short short4x;  // 8B
typedef __attribute__((ext_vector_type(4))) float float4x;  // MFMA C/D
typedef __hip_bfloat16 bf16;

#define EPS_F 1.1920929e-07f
#define SCALE_F 0.07216878364870323f   // 192^-0.5

// flag semantics: 0 = primary inputs are bf16, 1 = primary inputs are fp32
__device__ inline float rdv(const void* p, size_t i, int f32) {
  return f32 ? ((const float*)p)[i] : __bfloat162float(((const bf16*)p)[i]);
}

__device__ inline int4 pack8(const float* s) {   // 8 fp32 -> 8 bf16 (RNE) in one int4
  unsigned short h[8];
#pragma unroll
  for (int t = 0; t < 8; t++) {
    bf16 b = __float2bfloat16(s[t]);
    __builtin_memcpy(&h[t], &b, 2);
  }
  int4 r;
  r.x = (int)((unsigned)h[0] | ((unsigned)h[1] << 16));
  r.y = (int)((unsigned)h[2] | ((unsigned)h[3] << 16));
  r.z = (int)((unsigned)h[4] | ((unsigned)h[5] << 16));
  r.w = (int)((unsigned)h[6] | ((unsigned)h[7] << 16));
  return r;
}

// -------- dtype detector: x ~ N(0,1); bf16 bits have exp field in [118,130] --------
__global__ __launch_bounds__(256) void detect_dtype(const unsigned short* __restrict__ x,
                                                    int* __restrict__ flag) {
  int tid = threadIdx.x;
  int cnt = 0;
#pragma unroll
  for (int i = 0; i < 4; i++) {
    unsigned short u = x[tid * 4 + i];
    int e = (u >> 7) & 0xFF;
    cnt += (e >= 118 && e <= 130) ? 1 : 0;
  }
#pragma unroll
  for (int off = 1; off < 64; off <<= 1) cnt += __shfl_xor(cnt, off);
  __shared__ int red[4];
  if ((tid & 63) == 0) red[tid >> 6] = cnt;
  __syncthreads();
  if (tid == 0) flag[0] = ((red[0] + red[1] + red[2] + red[3]) > 768) ? 0 : 1;
}

__global__ __launch_bounds__(256) void sentinel_kernel(bf16* out, int n) {
  int i = blockIdx.x * 256 + threadIdx.x;
  if (i < n) out[i] = __float2bfloat16(1000.0f);
}

// ---------------- GEMM: C[M,N] = A[M,K] @ W[N,K]^T + bias[N] ----------------
// OMODE: 0 = fp32 store (internal), 1 = bf16 store (internal), 2 = flag-selected (d_out)
// A_DYN: A is a primary input (dtype per flag); otherwise internal bf16.
template<int OMODE, bool A_DYN>
__global__ __launch_bounds__(256) void gemm_bias(
    const void* __restrict__ A, const void* __restrict__ W,
    const void* __restrict__ bias, void* __restrict__ Cout,
    int M, int N, int K, const int* __restrict__ flagp)
{
  const int f32in = flagp[0];
  __shared__ int4 As[128 * 5];   // row = 32 bf16 = 4 int4, padded to 5
  __shared__ int4 Bs[128 * 5];
  const int tid = threadIdx.x;
  const int lane = tid & 63;
  const int wave = tid >> 6;
  const int grp = lane >> 4;
  const int l16 = lane & 15;
  const int m0 = blockIdx.x * 128;
  const int n0 = blockIdx.y * 128;
  const int wm = (wave & 1) * 64;
  const int wn = (wave >> 1) * 64;
  float4x acc[4][4] = {};
  for (int k0 = 0; k0 < K; k0 += 32) {
#pragma unroll
    for (int i = 0; i < 2; i++) {
      int chunk = tid + i * 256;      // 512 chunks of 8 elems per matrix
      int row = chunk >> 2;
      int kc = chunk & 3;
      int gm = m0 + row; if (gm > M - 1) gm = M - 1;  // clamp (stores guarded)
      int gn = n0 + row; if (gn > N - 1) gn = N - 1;
      size_t aoff = (size_t)gm * K + k0 + kc * 8;
      size_t boff = (size_t)gn * K + k0 + kc * 8;
      if (A_DYN && f32in) As[row * 5 + kc] = pack8((const float*)A + aoff);
      else                As[row * 5 + kc] = *(const int4*)((const bf16*)A + aoff);
      if (f32in)          Bs[row * 5 + kc] = pack8((const float*)W + boff);
      else                Bs[row * 5 + kc] = *(const int4*)((const bf16*)W + boff);
    }
    __syncthreads();
    short8x af[4], bfr[4];
#pragma unroll
    for (int i = 0; i < 4; i++) {
      af[i]  = *(const short8x*)&As[(wm + i * 16 + l16) * 5 + grp];
      bfr[i] = *(const short8x*)&Bs[(wn + i * 16 + l16) * 5 + grp];
    }
#pragma unroll
    for (int i = 0; i < 4; i++)
#pragma unroll
      for (int j = 0; j < 4; j++)
        acc[i][j] = __builtin_amdgcn_mfma_f32_16x16x32_bf16(af[i], bfr[j], acc[i][j], 0, 0, 0);
    __syncthreads();
  }
  // D layout: col=lane&15, row=(lane>>4)*4+r (m89/m91 verified)
#pragma unroll
  for (int j = 0; j < 4; j++) {
    int gn = n0 + wn + j * 16 + l16;
    if (gn >= N) continue;
    float bv = rdv(bias, gn, f32in);
#pragma unroll
    for (int i = 0; i < 4; i++) {
      int gm0 = m0 + wm + i * 16 + grp * 4;
#pragma unroll
      for (int r = 0; r < 4; r++) {
        int gm = gm0 + r;
        if (gm >= M) continue;
        float v = acc[i][j][r] + bv;
        size_t idx = (size_t)gm * N + gn;
        if (OMODE == 0)      ((float*)Cout)[idx] = v;
        else if (OMODE == 1) ((bf16*)Cout)[idx] = __float2bfloat16(v);
        else {
          if (f32in) ((float*)Cout)[idx] = v;
          else       ((bf16*)Cout)[idx] = __float2bfloat16(v);
        }
      }
    }
  }
}

// ---------------- RMSNorm over 512 fp32 -> bf16 ----------------
__global__ __launch_bounds__(256) void rmsnorm512(
    const float* __restrict__ in, const void* __restrict__ w,
    bf16* __restrict__ out, const int* __restrict__ flagp)
{
  const int f32in = flagp[0];
  const int s = blockIdx.x, tid = threadIdx.x;
  const float* row = in + (size_t)s * 512;
  float v0 = row[tid], v1 = row[tid + 256];
  float ss = v0 * v0 + v1 * v1;
#pragma unroll
  for (int off = 1; off < 64; off <<= 1) ss += __shfl_xor(ss, off);
  __shared__ float red[4];
  if ((tid & 63) == 0) red[tid >> 6] = ss;
  __syncthreads();
  float tot = red[0] + red[1] + red[2] + red[3];
  float scale = rsqrtf(tot * (1.0f / 512.0f) + EPS_F);
  out[(size_t)s * 512 + tid]       = __float2bfloat16(v0 * scale * rdv(w, tid, f32in));
  out[(size_t)s * 512 + tid + 256] = __float2bfloat16(v1 * scale * rdv(w, tid + 256, f32in));
}

// ---------------- kv_a post: rmsnorm(512) + rope(last 64) ----------------
__global__ __launch_bounds__(256) void kv_post(
    const float* __restrict__ kv, const void* __restrict__ w,
    const void* __restrict__ cosb, const void* __restrict__ sinb,
    bf16* __restrict__ kvn, bf16* __restrict__ kpe, const int* __restrict__ flagp)
{
  const int f32in = flagp[0];
  const int s = blockIdx.x, tid = threadIdx.x;
  const float* row = kv + (size_t)s * 576;
  float v0 = row[tid], v1 = row[tid + 256];
  float ss = v0 * v0 + v1 * v1;
#pragma unroll
  for (int off = 1; off < 64; off <<= 1) ss += __shfl_xor(ss, off);
  __shared__ float red[4];
  if ((tid & 63) == 0) red[tid >> 6] = ss;
  __syncthreads();
  float tot = red[0] + red[1] + red[2] + red[3];
  float scale = rsqrtf(tot * (1.0f / 512.0f) + EPS_F);
  kvn[(size_t)s * 512 + tid]       = __float2bfloat16(v0 * scale * rdv(w, tid, f32in));
  kvn[(size_t)s * 512 + tid + 256] = __float2bfloat16(v1 * scale * rdv(w, tid + 256, f32in));
  if (tid < 32) {
    float x0 = row[512 + 2 * tid], x1 = row[512 + 2 * tid + 1];
    float c  = rdv(cosb, (size_t)s * 32 + tid, f32in);
    float sn = rdv(sinb, (size_t)s * 32 + tid, f32in);
    kpe[s * 64 + 2 * tid]     = __float2bfloat16(x0 * c - x1 * sn);
    kpe[s * 64 + 2 * tid + 1] = __float2bfloat16(x0 * sn + x1 * c);
  }
}

// ---------------- in-place rope on q (S,3072): d in [128,192) of each head ----
__global__ __launch_bounds__(256) void rope_q_inplace(
    bf16* __restrict__ q, const void* __restrict__ cosb,
    const void* __restrict__ sinb, const int* __restrict__ flagp)
{
  const int f32in = flagp[0];
  const int s = blockIdx.x, tid = threadIdx.x;
#pragma unroll
  for (int it = 0; it < 2; it++) {
    int p = tid + it * 256;                 // rope pair index 0..511 (16 heads x 32)
    int hh = p >> 5, jj = p & 31;
    bf16* src = q + (size_t)s * 3072 + hh * 192 + 128 + 2 * jj;
    float x0 = __bfloat162float(src[0]);
    float x1 = __bfloat162float(src[1]);
    float c  = rdv(cosb, (size_t)s * 32 + jj, f32in);
    float sn = rdv(sinb, (size_t)s * 32 + jj, f32in);
    src[0] = __float2bfloat16(x0 * c - x1 * sn);
    src[1] = __float2bfloat16(x0 * sn + x1 * c);
  }
}

// ---------------- Vt (H,128,S) = transpose of v part of kvb ----------------
__global__ __launch_bounds__(256) void build_vt(
    const bf16* __restrict__ kvb, bf16* __restrict__ Vt)
{
  __shared__ __align__(16) bf16 tile[64][136];
  const int h = blockIdx.x;
  const int t0 = blockIdx.y * 64;
  const int tid = threadIdx.x;
#pragma unroll
  for (int i = 0; i < 4; i++) {
    int chunk = tid + i * 256;          // 1024 chunks of 8 bf16
    int row = chunk >> 4;
    int c8 = (chunk & 15) * 8;
    *(int4*)&tile[row][c8] =
        *(const int4*)(kvb + (size_t)(t0 + row) * 4096 + h * 256 + 128 + c8);
  }
  __syncthreads();
#pragma unroll
  for (int i = 0; i < 32; i++) {
    int idx = tid + i * 256;            // 8192 elems
    int d = idx >> 6;
    int t = idx & 63;
    Vt[((size_t)h * 128 + d) * 2048 + t0 + t] = tile[t][d];
  }
}

// ---------------- flash attention: block = (head, 64 q rows), 4 waves -------
__global__ __launch_bounds__(256) void attn_kernel(
    const bf16* __restrict__ Q, const bf16* __restrict__ kvb,
    const bf16* __restrict__ kpe, const bf16* __restrict__ Vt,
    bf16* __restrict__ Out)
{
  __shared__ __align__(16) bf16 plds[4][16 * 68];  // per-wave P 16x64, stride 68
  const int h = blockIdx.x;
  const int q0 = blockIdx.y * 64;
  const int tid = threadIdx.x;
  const int wave = tid >> 6;
  const int lane = tid & 63;
  const int grp = lane >> 4, l16 = lane & 15;
  const int qrt = q0 + wave * 16;
  const bf16* Qbase = Q + (size_t)(qrt + l16) * 3072 + h * 192;
  short8x qf[6];                                   // Q fragments, loaded once
#pragma unroll
  for (int c = 0; c < 6; c++)
    qf[c] = *(const short8x*)(Qbase + c * 32 + grp * 8);
  float m_run[4], l_run[4];
  float4x o_acc[8] = {};
#pragma unroll
  for (int r = 0; r < 4; r++) { m_run[r] = -__builtin_inff(); l_run[r] = 0.f; }
  bf16* pl = &plds[wave][0];
  for (int t0 = 0; t0 <= q0; t0 += 64) {
    // S = Q K^T for 16x64 tile; K = concat(kvb nope, shared kpe)
    float4x sacc[4] = {};
#pragma unroll
    for (int n = 0; n < 4; n++) {
      const int trow = t0 + n * 16 + l16;
      const bf16* Kb = kvb + (size_t)trow * 4096 + h * 256 + grp * 8;
      const bf16* Pb = kpe + (size_t)trow * 64 + grp * 8;
      short8x kf;
      kf = *(const short8x*)(Kb);       sacc[n] = __builtin_amdgcn_mfma_f32_16x16x32_bf16(qf[0], kf, sacc[n], 0, 0, 0);
      kf = *(const short8x*)(Kb + 32);  sacc[n] = __builtin_amdgcn_mfma_f32_16x16x32_bf16(qf[1], kf, sacc[n], 0, 0, 0);
      kf = *(const short8x*)(Kb + 64);  sacc[n] = __builtin_amdgcn_mfma_f32_16x16x32_bf16(qf[2], kf, sacc[n], 0, 0, 0);
      kf = *(const short8x*)(Kb + 96);  sacc[n] = __builtin_amdgcn_mfma_f32_16x16x32_bf16(qf[3], kf, sacc[n], 0, 0, 0);
      kf = *(const short8x*)(Pb);       sacc[n] = __builtin_amdgcn_mfma_f32_16x16x32_bf16(qf[4], kf, sacc[n], 0, 0, 0);
      kf = *(const short8x*)(Pb + 32);  sacc[n] = __builtin_amdgcn_mfma_f32_16x16x32_bf16(qf[5], kf, sacc[n], 0, 0, 0);
    }
    // scale + causal mask + online softmax (row r held by 16 lanes sharing grp)
    float pv[4][4], alpha[4];
#pragma unroll
    for (int r = 0; r < 4; r++) {
      const int s_row = qrt + grp * 4 + r;
      float p0[4];
      float mx = -__builtin_inff();
#pragma unroll
      for (int n = 0; n < 4; n++) {
        int t = t0 + n * 16 + l16;
        float v = sacc[n][r] * SCALE_F;
        v = (t > s_row) ? -1.0e9f : v;
        p0[n] = v;
        mx = fmaxf(mx, v);
      }
      mx = fmaxf(mx, __shfl_xor(mx, 1));
      mx = fmaxf(mx, __shfl_xor(mx, 2));
      mx = fmaxf(mx, __shfl_xor(mx, 4));
      mx = fmaxf(mx, __shfl_xor(mx, 8));
      float m_new = fmaxf(m_run[r], mx);
      float a = __expf(m_run[r] - m_new);
      m_run[r] = m_new;
      float sum = 0.f;
#pragma unroll
      for (int n = 0; n < 4; n++) {
        float e = __expf(p0[n] - m_new);
        pv[n][r] = e;
        sum += e;
      }
      sum += __shfl_xor(sum, 1);
      sum += __shfl_xor(sum, 2);
      sum += __shfl_xor(sum, 4);
      sum += __shfl_xor(sum, 8);
      l_run[r] = l_run[r] * a + sum;
      alpha[r] = a;
    }
#pragma unroll
    for (int n = 0; n < 8; n++)
#pragma unroll
      for (int r = 0; r < 4; r++)
        o_acc[n][r] *= alpha[r];
    // P: D-layout -> LDS -> A-layout (m120-verified transform)
#pragma unroll
    for (int n = 0; n < 4; n++)
#pragma unroll
      for (int r = 0; r < 4; r++)
        pl[(grp * 4 + r) * 68 + n * 16 + l16] = __float2bfloat16(pv[n][r]);
    __syncthreads();
#pragma unroll
    for (int c = 0; c < 2; c++) {
      union { short4x h4[2]; short8x v8; } pk;
      const bf16* pp = pl + l16 * 68 + c * 32 + grp * 8;
      pk.h4[0] = *(const short4x*)(pp);
      pk.h4[1] = *(const short4x*)(pp + 4);
#pragma unroll
      for (int n = 0; n < 8; n++) {
        const bf16* Vb = Vt + ((size_t)h * 128 + n * 16 + l16) * 2048 + t0 + c * 32 + grp * 8;
        short8x vf = *(const short8x*)Vb;
        o_acc[n] = __builtin_amdgcn_mfma_f32_16x16x32_bf16(pk.v8, vf, o_acc[n], 0, 0, 0);
      }
    }
    __syncthreads();
  }
  float inv[4];
#pragma unroll
  for (int r = 0; r < 4; r++) inv[r] = 1.0f / l_run[r];
#pragma unroll
  for (int n = 0; n < 8; n++)
#pragma unroll
    for (int r = 0; r < 4; r++) {
      int s_row = qrt + grp * 4 + r;
      Out[(size_t)s_row * 2048 + h * 128 + n * 16 + l16] =
          __float2bfloat16(o_acc[n][r] * inv[r]);
    }
}

extern "C" void kernel_launch(void* const* d_in, const int* in_sizes, int n_in,
                              void* d_out, int out_size, void* d_ws, size_t ws_size,
                              hipStream_t stream) {
  const void* x        = d_in[0];
  const void* fcos     = d_in[2];
  const void* fsin     = d_in[3];
  const void* wq_a_w   = d_in[5];
  const void* wq_a_b   = d_in[6];
  const void* q_norm_w = d_in[7];
  const void* wq_b_w   = d_in[8];
  const void* wq_b_b   = d_in[9];
  const void* wkv_a_w  = d_in[10];
  const void* wkv_a_b  = d_in[11];
  const void* kv_norm_w= d_in[12];
  const void* wkv_b_w  = d_in[13];
  const void* wkv_b_b  = d_in[14];
  const void* wo_w     = d_in[15];
  const void* wo_b     = d_in[16];

  const size_t MB = 1024 * 1024;
  if (ws_size < 46 * MB) {   // diagnostic: absmax ~1000 next round => ws too small
    sentinel_kernel<<<(out_size + 255) / 256, 256, 0, stream>>>((bf16*)d_out, out_size);
    return;
  }
  char* ws = (char*)d_ws;
  int*   flag   = (int*)(ws);                      // [0, 4B)
  float* q_a    = (float*)(ws + 1 * MB);           // [1,5)   fp32 2048x512
  bf16*  qn     = (bf16*)(ws + 5 * MB);            // [5,7)
  float* kv_a   = (float*)(ws + 1 * MB);           // [1,5.5) fp32 2048x576 (q_a/qn dead)
  bf16*  kvn    = (bf16*)(ws + 6 * MB);            // [6,8)
  bf16*  attnout= (bf16*)(ws + 1 * MB);            // [1,9)   (kv_a/kvn dead)
  bf16*  qbuf   = (bf16*)(ws + 9 * MB);            // [9,21)  2048x3072, roped in place
  bf16*  kvb    = (bf16*)(ws + 21 * MB);           // [21,37) 2048x4096
  bf16*  Vt     = (bf16*)(ws + 37 * MB);           // [37,45) 16x128x2048
  bf16*  kpe    = (bf16*)(ws + 45 * MB);           // [45,45.25) 2048x64

  dim3 blk(256);
  detect_dtype<<<1, blk, 0, stream>>>((const unsigned short*)x, flag);
  // Q branch
  gemm_bias<0, true ><<<dim3(16,  4), blk, 0, stream>>>(x,   wq_a_w,  wq_a_b,  q_a,  2048,  512, 2048, flag);
  rmsnorm512<<<2048, blk, 0, stream>>>(q_a, q_norm_w, qn, flag);
  gemm_bias<1, false><<<dim3(16, 24), blk, 0, stream>>>(qn,  wq_b_w,  wq_b_b,  qbuf, 2048, 3072,  512, flag);
  rope_q_inplace<<<2048, blk, 0, stream>>>(qbuf, fcos, fsin, flag);
  // KV branch
  gemm_bias<0, true ><<<dim3(16,  5), blk, 0, stream>>>(x,   wkv_a_w, wkv_a_b, kv_a, 2048,  576, 2048, flag);
  kv_post<<<2048, blk, 0, stream>>>(kv_a, kv_norm_w, fcos, fsin, kvn, kpe, flag);
  gemm_bias<1, false><<<dim3(16, 32), blk, 0, stream>>>(kvn, wkv_b_w, wkv_b_b, kvb,  2048, 4096,  512, flag);
  build_vt<<<dim3(16, 32), blk, 0, stream>>>(kvb, Vt);
  // Attention + output projection
  attn_kernel<<<dim3(16, 32), blk, 0, stream>>>(qbuf, kvb, kpe, Vt, attnout);
  gemm_bias<2, false><<<dim3(16, 16), blk, 0, stream>>>(attnout, wo_w, wo_b, d_out, 2048, 2048, 2048, flag);
}

// Round 3
// 450.562 us; speedup vs baseline: 1.7958x; 1.7958x over previous
//
#include <hip/hip_runtime.h>
#include <hip/hip_bf16.h>

typedef __attribute__((ext_vector_type(8))) short short8x;  // 8 bf16 = 4 VGPR
typedef __attribute__((ext_vector_type(4))) short short4x;  // 8B
typedef __attribute__((ext_vector_type(4))) float float4x;  // MFMA C/D
typedef __hip_bfloat16 bf16;

#define EPS_F 1.1920929e-07f
#define SCALE_F 0.07216878364870323f   // 192^-0.5

// flag semantics: 0 = primary inputs are bf16, 1 = primary inputs are fp32
__device__ inline float rdv(const void* p, size_t i, int f32) {
  return f32 ? ((const float*)p)[i] : __bfloat162float(((const bf16*)p)[i]);
}

__device__ inline int4 pack8(const float* s) {   // 8 fp32 -> 8 bf16 (RNE)
  unsigned short h[8];
#pragma unroll
  for (int t = 0; t < 8; t++) {
    bf16 b = __float2bfloat16(s[t]);
    __builtin_memcpy(&h[t], &b, 2);
  }
  int4 r;
  r.x = (int)((unsigned)h[0] | ((unsigned)h[1] << 16));
  r.y = (int)((unsigned)h[2] | ((unsigned)h[3] << 16));
  r.z = (int)((unsigned)h[4] | ((unsigned)h[5] << 16));
  r.w = (int)((unsigned)h[6] | ((unsigned)h[7] << 16));
  return r;
}

// async global->LDS, 16B per lane; LDS dest = wave-uniform base + lane*16
typedef __attribute__((address_space(1))) const unsigned int gu32;
typedef __attribute__((address_space(3))) unsigned int lu32;
__device__ __forceinline__ void gload16(const void* g, void* l) {
  __builtin_amdgcn_global_load_lds((gu32*)g, (lu32*)l, 16, 0, 0);
}

// -------- dtype detector: x ~ N(0,1); bf16 bits have exp field in [118,130] --------
__global__ __launch_bounds__(256) void detect_dtype(const unsigned short* __restrict__ x,
                                                    int* __restrict__ flag) {
  int tid = threadIdx.x;
  int cnt = 0;
#pragma unroll
  for (int i = 0; i < 4; i++) {
    unsigned short u = x[tid * 4 + i];
    int e = (u >> 7) & 0xFF;
    cnt += (e >= 118 && e <= 130) ? 1 : 0;
  }
#pragma unroll
  for (int off = 1; off < 64; off <<= 1) cnt += __shfl_xor(cnt, off);
  __shared__ int red[4];
  if ((tid & 63) == 0) red[tid >> 6] = cnt;
  __syncthreads();
  if (tid == 0) flag[0] = ((red[0] + red[1] + red[2] + red[3]) > 768) ? 0 : 1;
}

__global__ __launch_bounds__(256) void sentinel_kernel(bf16* out, int n) {
  int i = blockIdx.x * 256 + threadIdx.x;
  if (i < n) out[i] = __float2bfloat16(1000.0f);
}

// ---------------- GEMM 128x128: C[M,N] = A[M,K] @ W[N,K]^T + bias[N] --------
// Staging: global_load_lds 16B, XOR-swizzled cols (c ^ (row>>1)&3), no pad.
// M, N must be multiples of 128. OMODE: 0=f32 out, 1=bf16 out, 2=flag dtype.
template<int OMODE, bool A_DYN>
__global__ __launch_bounds__(256) void gemm128(
    const void* __restrict__ A, const void* __restrict__ W,
    const void* __restrict__ bias, void* __restrict__ Cout,
    int M, int N, int K, const int* __restrict__ flagp)
{
  const int f32in = flagp[0];
  __shared__ int4 As4[128 * 4];
  __shared__ int4 Bs4[128 * 4];
  const int tid = threadIdx.x, lane = tid & 63, wave = tid >> 6;
  const int grp = lane >> 4, l16 = lane & 15;
  const int m0 = blockIdx.x * 128, n0 = blockIdx.y * 128;
  const int wm = (wave & 1) * 64, wn = (wave >> 1) * 64;
  float4x acc[4][4] = {};
  for (int k0 = 0; k0 < K; k0 += 32) {
    if (!f32in) {
#pragma unroll
      for (int j = 0; j < 2; j++) {
        int row = wave * 32 + j * 16 + (lane >> 2);
        int cs = (lane & 3) ^ ((row >> 1) & 3);
        gload16((const bf16*)A + (size_t)(m0 + row) * K + k0 + cs * 8,
                &As4[(wave * 32 + j * 16) * 4]);
        gload16((const bf16*)W + (size_t)(n0 + row) * K + k0 + cs * 8,
                &Bs4[(wave * 32 + j * 16) * 4]);
      }
    } else {
#pragma unroll
      for (int i = 0; i < 2; i++) {
        int ch = tid + i * 256;          // 512 chunks per matrix
        int row = ch >> 2, c = ch & 3;
        int cs = c ^ ((row >> 1) & 3);
        size_t aoff = (size_t)(m0 + row) * K + k0 + cs * 8;
        size_t boff = (size_t)(n0 + row) * K + k0 + cs * 8;
        As4[row * 4 + c] = A_DYN ? pack8((const float*)A + aoff)
                                 : *(const int4*)((const bf16*)A + aoff);
        Bs4[row * 4 + c] = pack8((const float*)W + boff);
      }
    }
    __syncthreads();    // drains vmcnt (incl. global_load_lds) before use
    short8x af[4], bfr[4];
#pragma unroll
    for (int i = 0; i < 4; i++) {
      int ra = wm + i * 16 + l16;
      int rb = wn + i * 16 + l16;
      af[i]  = *(const short8x*)&As4[ra * 4 + (grp ^ ((ra >> 1) & 3))];
      bfr[i] = *(const short8x*)&Bs4[rb * 4 + (grp ^ ((rb >> 1) & 3))];
    }
#pragma unroll
    for (int i = 0; i < 4; i++)
#pragma unroll
      for (int j = 0; j < 4; j++)
        acc[i][j] = __builtin_amdgcn_mfma_f32_16x16x32_bf16(af[i], bfr[j], acc[i][j], 0, 0, 0);
    __syncthreads();
  }
  // D layout: col=lane&15, row=(lane>>4)*4+r
#pragma unroll
  for (int j = 0; j < 4; j++) {
    int gn = n0 + wn + j * 16 + l16;
    float bv = rdv(bias, gn, f32in);
#pragma unroll
    for (int i = 0; i < 4; i++) {
      int gm0 = m0 + wm + i * 16 + grp * 4;
#pragma unroll
      for (int r = 0; r < 4; r++) {
        float v = acc[i][j][r] + bv;
        size_t idx = (size_t)(gm0 + r) * N + gn;
        if (OMODE == 0)      ((float*)Cout)[idx] = v;
        else if (OMODE == 1) ((bf16*)Cout)[idx] = __float2bfloat16(v);
        else {
          if (f32in) ((float*)Cout)[idx] = v;
          else       ((bf16*)Cout)[idx] = __float2bfloat16(v);
        }
      }
    }
  }
}

// ---------------- GEMM 64x64 (small-N shapes; 4x the blocks of 128x128) -----
template<int OMODE, bool A_DYN>
__global__ __launch_bounds__(256) void gemm64(
    const void* __restrict__ A, const void* __restrict__ W,
    const void* __restrict__ bias, void* __restrict__ Cout,
    int M, int N, int K, const int* __restrict__ flagp)
{
  const int f32in = flagp[0];
  __shared__ int4 As4[64 * 4];
  __shared__ int4 Bs4[64 * 4];
  const int tid = threadIdx.x, lane = tid & 63, wave = tid >> 6;
  const int grp = lane >> 4, l16 = lane & 15;
  const int m0 = blockIdx.x * 64, n0 = blockIdx.y * 64;
  const int wm = (wave & 1) * 32, wn = (wave >> 1) * 32;
  float4x acc[2][2] = {};
  for (int k0 = 0; k0 < K; k0 += 32) {
    if (!f32in) {
      int row = wave * 16 + (lane >> 2);
      int cs = (lane & 3) ^ ((row >> 1) & 3);
      gload16((const bf16*)A + (size_t)(m0 + row) * K + k0 + cs * 8,
              &As4[wave * 16 * 4]);
      gload16((const bf16*)W + (size_t)(n0 + row) * K + k0 + cs * 8,
              &Bs4[wave * 16 * 4]);
    } else {
      int row = tid >> 2, c = tid & 3;        // 256 chunks per matrix
      int cs = c ^ ((row >> 1) & 3);
      size_t aoff = (size_t)(m0 + row) * K + k0 + cs * 8;
      size_t boff = (size_t)(n0 + row) * K + k0 + cs * 8;
      As4[row * 4 + c] = A_DYN ? pack8((const float*)A + aoff)
                               : *(const int4*)((const bf16*)A + aoff);
      Bs4[row * 4 + c] = pack8((const float*)W + boff);
    }
    __syncthreads();
    short8x af[2], bfr[2];
#pragma unroll
    for (int i = 0; i < 2; i++) {
      int ra = wm + i * 16 + l16;
      int rb = wn + i * 16 + l16;
      af[i]  = *(const short8x*)&As4[ra * 4 + (grp ^ ((ra >> 1) & 3))];
      bfr[i] = *(const short8x*)&Bs4[rb * 4 + (grp ^ ((rb >> 1) & 3))];
    }
#pragma unroll
    for (int i = 0; i < 2; i++)
#pragma unroll
      for (int j = 0; j < 2; j++)
        acc[i][j] = __builtin_amdgcn_mfma_f32_16x16x32_bf16(af[i], bfr[j], acc[i][j], 0, 0, 0);
    __syncthreads();
  }
#pragma unroll
  for (int j = 0; j < 2; j++) {
    int gn = n0 + wn + j * 16 + l16;
    float bv = rdv(bias, gn, f32in);
#pragma unroll
    for (int i = 0; i < 2; i++) {
      int gm0 = m0 + wm + i * 16 + grp * 4;
#pragma unroll
      for (int r = 0; r < 4; r++) {
        float v = acc[i][j][r] + bv;
        size_t idx = (size_t)(gm0 + r) * N + gn;
        if (OMODE == 0)      ((float*)Cout)[idx] = v;
        else if (OMODE == 1) ((bf16*)Cout)[idx] = __float2bfloat16(v);
        else {
          if (f32in) ((float*)Cout)[idx] = v;
          else       ((bf16*)Cout)[idx] = __float2bfloat16(v);
        }
      }
    }
  }
}

// ---------------- RMSNorm over 512 fp32 -> bf16 ----------------
__global__ __launch_bounds__(256) void rmsnorm512(
    const float* __restrict__ in, const void* __restrict__ w,
    bf16* __restrict__ out, const int* __restrict__ flagp)
{
  const int f32in = flagp[0];
  const int s = blockIdx.x, tid = threadIdx.x;
  const float* row = in + (size_t)s * 512;
  float v0 = row[tid], v1 = row[tid + 256];
  float ss = v0 * v0 + v1 * v1;
#pragma unroll
  for (int off = 1; off < 64; off <<= 1) ss += __shfl_xor(ss, off);
  __shared__ float red[4];
  if ((tid & 63) == 0) red[tid >> 6] = ss;
  __syncthreads();
  float tot = red[0] + red[1] + red[2] + red[3];
  float scale = rsqrtf(tot * (1.0f / 512.0f) + EPS_F);
  out[(size_t)s * 512 + tid]       = __float2bfloat16(v0 * scale * rdv(w, tid, f32in));
  out[(size_t)s * 512 + tid + 256] = __float2bfloat16(v1 * scale * rdv(w, tid + 256, f32in));
}

// ---------------- kv_a post: rmsnorm(512) + rope(last 64) ----------------
__global__ __launch_bounds__(256) void kv_post(
    const float* __restrict__ kv, const void* __restrict__ w,
    const void* __restrict__ cosb, const void* __restrict__ sinb,
    bf16* __restrict__ kvn, bf16* __restrict__ kpe, const int* __restrict__ flagp)
{
  const int f32in = flagp[0];
  const int s = blockIdx.x, tid = threadIdx.x;
  const float* row = kv + (size_t)s * 576;
  float v0 = row[tid], v1 = row[tid + 256];
  float ss = v0 * v0 + v1 * v1;
#pragma unroll
  for (int off = 1; off < 64; off <<= 1) ss += __shfl_xor(ss, off);
  __shared__ float red[4];
  if ((tid & 63) == 0) red[tid >> 6] = ss;
  __syncthreads();
  float tot = red[0] + red[1] + red[2] + red[3];
  float scale = rsqrtf(tot * (1.0f / 512.0f) + EPS_F);
  kvn[(size_t)s * 512 + tid]       = __float2bfloat16(v0 * scale * rdv(w, tid, f32in));
  kvn[(size_t)s * 512 + tid + 256] = __float2bfloat16(v1 * scale * rdv(w, tid + 256, f32in));
  if (tid < 32) {
    float x0 = row[512 + 2 * tid], x1 = row[512 + 2 * tid + 1];
    float c  = rdv(cosb, (size_t)s * 32 + tid, f32in);
    float sn = rdv(sinb, (size_t)s * 32 + tid, f32in);
    kpe[s * 64 + 2 * tid]     = __float2bfloat16(x0 * c - x1 * sn);
    kpe[s * 64 + 2 * tid + 1] = __float2bfloat16(x0 * sn + x1 * c);
  }
}

// ---------------- in-place rope on q (S,3072): d in [128,192) of each head ----
__global__ __launch_bounds__(256) void rope_q_inplace(
    bf16* __restrict__ q, const void* __restrict__ cosb,
    const void* __restrict__ sinb, const int* __restrict__ flagp)
{
  const int f32in = flagp[0];
  const int s = blockIdx.x, tid = threadIdx.x;
#pragma unroll
  for (int it = 0; it < 2; it++) {
    int p = tid + it * 256;                 // rope pair index (16 heads x 32)
    int hh = p >> 5, jj = p & 31;
    bf16* src = q + (size_t)s * 3072 + hh * 192 + 128 + 2 * jj;
    float x0 = __bfloat162float(src[0]);
    float x1 = __bfloat162float(src[1]);
    float c  = rdv(cosb, (size_t)s * 32 + jj, f32in);
    float sn = rdv(sinb, (size_t)s * 32 + jj, f32in);
    src[0] = __float2bfloat16(x0 * c - x1 * sn);
    src[1] = __float2bfloat16(x0 * sn + x1 * c);
  }
}

// ---------------- Vt (H,128,S) = transpose of v part of kvb ----------------
__global__ __launch_bounds__(256) void build_vt(
    const bf16* __restrict__ kvb, bf16* __restrict__ Vt)
{
  __shared__ __align__(16) bf16 tile[64][136];
  const int h = blockIdx.x;
  const int t0 = blockIdx.y * 64;
  const int tid = threadIdx.x;
#pragma unroll
  for (int i = 0; i < 4; i++) {
    int chunk = tid + i * 256;          // 1024 chunks of 8 bf16
    int row = chunk >> 4;
    int c8 = (chunk & 15) * 8;
    *(int4*)&tile[row][c8] =
        *(const int4*)(kvb + (size_t)(t0 + row) * 4096 + h * 256 + 128 + c8);
  }
  __syncthreads();
#pragma unroll
  for (int i = 0; i < 32; i++) {
    int idx = tid + i * 256;            // 8192 elems
    int d = idx >> 6;
    int t = idx & 63;
    Vt[((size_t)h * 128 + d) * 2048 + t0 + t] = tile[t][d];
  }
}

// ---------------- flash attention: block = (head, 64 q rows), 4 waves -------
// K/V tiles staged in LDS, shared by all 4 waves.
__global__ __launch_bounds__(256) void attn_kernel(
    const bf16* __restrict__ Q, const bf16* __restrict__ kvb,
    const bf16* __restrict__ kpe, const bf16* __restrict__ Vt,
    bf16* __restrict__ Out)
{
  __shared__ __align__(16) bf16 Ks[64 * 200];      // 64 rows x 192, pad->200
  __shared__ __align__(16) bf16 Vs[128 * 72];      // 128 d-rows x 64, pad->72
  __shared__ __align__(16) bf16 plds[4][16 * 68];  // per-wave P 16x64, stride 68
  const int h = blockIdx.x;
  const int q0 = blockIdx.y * 64;
  const int tid = threadIdx.x;
  const int wave = tid >> 6;
  const int lane = tid & 63;
  const int grp = lane >> 4, l16 = lane & 15;
  const int qrt = q0 + wave * 16;
  const bf16* Qbase = Q + (size_t)(qrt + l16) * 3072 + h * 192;
  short8x qf[6];                                   // Q fragments, loaded once
#pragma unroll
  for (int c = 0; c < 6; c++)
    qf[c] = *(const short8x*)(Qbase + c * 32 + grp * 8);
  float m_run[4], l_run[4];
  float4x o_acc[8] = {};
#pragma unroll
  for (int r = 0; r < 4; r++) { m_run[r] = -__builtin_inff(); l_run[r] = 0.f; }
  bf16* pl = &plds[wave][0];
  for (int t0 = 0; t0 <= q0; t0 += 64) {
    // ---- cooperative stage: K nope (64x128), K rope (64x64), V (128x64) ----
#pragma unroll
    for (int i = 0; i < 4; i++) {
      int ch = tid + i * 256;                      // 1024 int4
      int row = ch >> 4, c = ch & 15;
      *(int4*)&Ks[row * 200 + c * 8] =
          *(const int4*)(kvb + (size_t)(t0 + row) * 4096 + h * 256 + c * 8);
    }
#pragma unroll
    for (int i = 0; i < 2; i++) {
      int ch = tid + i * 256;                      // 512 int4
      int row = ch >> 3, c = ch & 7;
      *(int4*)&Ks[row * 200 + 128 + c * 8] =
          *(const int4*)(kpe + (size_t)(t0 + row) * 64 + c * 8);
    }
#pragma unroll
    for (int i = 0; i < 4; i++) {
      int ch = tid + i * 256;                      // 1024 int4
      int row = ch >> 3, c = ch & 7;
      *(int4*)&Vs[row * 72 + c * 8] =
          *(const int4*)(Vt + ((size_t)h * 128 + row) * 2048 + t0 + c * 8);
    }
    __syncthreads();
    // ---- S = Q K^T (fragments from LDS) ----
    float4x sacc[4] = {};
#pragma unroll
    for (int n = 0; n < 4; n++) {
      const bf16* Kb = &Ks[(n * 16 + l16) * 200 + grp * 8];
#pragma unroll
      for (int c = 0; c < 6; c++) {
        short8x kf = *(const short8x*)(Kb + c * 32);
        sacc[n] = __builtin_amdgcn_mfma_f32_16x16x32_bf16(qf[c], kf, sacc[n], 0, 0, 0);
      }
    }
    // ---- scale + causal mask + online softmax ----
    float pv[4][4], alpha[4];
#pragma unroll
    for (int r = 0; r < 4; r++) {
      const int s_row = qrt + grp * 4 + r;
      float p0[4];
      float mx = -__builtin_inff();
#pragma unroll
      for (int n = 0; n < 4; n++) {
        int t = t0 + n * 16 + l16;
        float v = sacc[n][r] * SCALE_F;
        v = (t > s_row) ? -1.0e9f : v;
        p0[n] = v;
        mx = fmaxf(mx, v);
      }
      mx = fmaxf(mx, __shfl_xor(mx, 1));
      mx = fmaxf(mx, __shfl_xor(mx, 2));
      mx = fmaxf(mx, __shfl_xor(mx, 4));
      mx = fmaxf(mx, __shfl_xor(mx, 8));
      float m_new = fmaxf(m_run[r], mx);
      float a = __expf(m_run[r] - m_new);
      m_run[r] = m_new;
      float sum = 0.f;
#pragma unroll
      for (int n = 0; n < 4; n++) {
        float e = __expf(p0[n] - m_new);
        pv[n][r] = e;
        sum += e;
      }
      sum += __shfl_xor(sum, 1);
      sum += __shfl_xor(sum, 2);
      sum += __shfl_xor(sum, 4);
      sum += __shfl_xor(sum, 8);
      l_run[r] = l_run[r] * a + sum;
      alpha[r] = a;
    }
#pragma unroll
    for (int n = 0; n < 8; n++)
#pragma unroll
      for (int r = 0; r < 4; r++)
        o_acc[n][r] *= alpha[r];
    // ---- P: D-layout -> per-wave LDS -> A-layout (no block barrier needed) ----
#pragma unroll
    for (int n = 0; n < 4; n++)
#pragma unroll
      for (int r = 0; r < 4; r++)
        pl[(grp * 4 + r) * 68 + n * 16 + l16] = __float2bfloat16(pv[n][r]);
#pragma unroll
    for (int c = 0; c < 2; c++) {
      union { short4x h4[2]; short8x v8; } pk;
      const bf16* pp = pl + l16 * 68 + c * 32 + grp * 8;
      pk.h4[0] = *(const short4x*)(pp);
      pk.h4[1] = *(const short4x*)(pp + 4);
#pragma unroll
      for (int n = 0; n < 8; n++) {
        short8x vf = *(const short8x*)&Vs[(size_t)(n * 16 + l16) * 72 + c * 32 + grp * 8];
        o_acc[n] = __builtin_amdgcn_mfma_f32_16x16x32_bf16(pk.v8, vf, o_acc[n], 0, 0, 0);
      }
    }
    __syncthreads();
  }
  float inv[4];
#pragma unroll
  for (int r = 0; r < 4; r++) inv[r] = 1.0f / l_run[r];
#pragma unroll
  for (int n = 0; n < 8; n++)
#pragma unroll
    for (int r = 0; r < 4; r++) {
      int s_row = qrt + grp * 4 + r;
      Out[(size_t)s_row * 2048 + h * 128 + n * 16 + l16] =
          __float2bfloat16(o_acc[n][r] * inv[r]);
    }
}

extern "C" void kernel_launch(void* const* d_in, const int* in_sizes, int n_in,
                              void* d_out, int out_size, void* d_ws, size_t ws_size,
                              hipStream_t stream) {
  const void* x        = d_in[0];
  const void* fcos     = d_in[2];
  const void* fsin     = d_in[3];
  const void* wq_a_w   = d_in[5];
  const void* wq_a_b   = d_in[6];
  const void* q_norm_w = d_in[7];
  const void* wq_b_w   = d_in[8];
  const void* wq_b_b   = d_in[9];
  const void* wkv_a_w  = d_in[10];
  const void* wkv_a_b  = d_in[11];
  const void* kv_norm_w= d_in[12];
  const void* wkv_b_w  = d_in[13];
  const void* wkv_b_b  = d_in[14];
  const void* wo_w     = d_in[15];
  const void* wo_b     = d_in[16];

  const size_t MB = 1024 * 1024;
  if (ws_size < 46 * MB) {   // diagnostic: absmax ~1000 => ws too small
    sentinel_kernel<<<(out_size + 255) / 256, 256, 0, stream>>>((bf16*)d_out, out_size);
    return;
  }
  char* ws = (char*)d_ws;
  int*   flag   = (int*)(ws);                      // [0, 4B)
  float* q_a    = (float*)(ws + 1 * MB);           // [1,5)   fp32 2048x512
  bf16*  qn     = (bf16*)(ws + 5 * MB);            // [5,7)
  float* kv_a   = (float*)(ws + 1 * MB);           // [1,5.5) fp32 2048x576 (q_a/qn dead)
  bf16*  kvn    = (bf16*)(ws + 6 * MB);            // [6,8)
  bf16*  attnout= (bf16*)(ws + 1 * MB);            // [1,9)   (kv_a/kvn dead)
  bf16*  qbuf   = (bf16*)(ws + 9 * MB);            // [9,21)  2048x3072, roped in place
  bf16*  kvb    = (bf16*)(ws + 21 * MB);           // [21,37) 2048x4096
  bf16*  Vt     = (bf16*)(ws + 37 * MB);           // [37,45) 16x128x2048
  bf16*  kpe    = (bf16*)(ws + 45 * MB);           // [45,45.25) 2048x64

  dim3 blk(256);
  detect_dtype<<<1, blk, 0, stream>>>((const unsigned short*)x, flag);
  // Q branch
  gemm64 <0, true ><<<dim3(32,  8), blk, 0, stream>>>(x,   wq_a_w,  wq_a_b,  q_a,  2048,  512, 2048, flag);
  rmsnorm512<<<2048, blk, 0, stream>>>(q_a, q_norm_w, qn, flag);
  gemm128<1, false><<<dim3(16, 24), blk, 0, stream>>>(qn,  wq_b_w,  wq_b_b,  qbuf, 2048, 3072,  512, flag);
  rope_q_inplace<<<2048, blk, 0, stream>>>(qbuf, fcos, fsin, flag);
  // KV branch
  gemm64 <0, true ><<<dim3(32,  9), blk, 0, stream>>>(x,   wkv_a_w, wkv_a_b, kv_a, 2048,  576, 2048, flag);
  kv_post<<<2048, blk, 0, stream>>>(kv_a, kv_norm_w, fcos, fsin, kvn, kpe, flag);
  gemm128<1, false><<<dim3(16, 32), blk, 0, stream>>>(kvn, wkv_b_w, wkv_b_b, kvb,  2048, 4096,  512, flag);
  build_vt<<<dim3(16, 32), blk, 0, stream>>>(kvb, Vt);
  // Attention + output projection
  attn_kernel<<<dim3(16, 32), blk, 0, stream>>>(qbuf, kvb, kpe, Vt, attnout);
  gemm128<2, false><<<dim3(16, 16), blk, 0, stream>>>(attnout, wo_w, wo_b, d_out, 2048, 2048, 2048, flag);
}

// Round 7
// 434.965 us; speedup vs baseline: 1.8602x; 1.0359x over previous
//
#include <hip/hip_runtime.h>
#include <hip/hip_bf16.h>

typedef __attribute__((ext_vector_type(8))) short short8x;  // 8 bf16 = 4 VGPR
typedef __attribute__((ext_vector_type(4))) short short4x;  // 8B
typedef __attribute__((ext_vector_type(4))) float float4x;  // MFMA C/D
typedef __hip_bfloat16 bf16;

#define EPS_F 1.1920929e-07f
#define SCALE_F 0.07216878364870323f   // 192^-0.5

// flag semantics: 0 = primary inputs are bf16, 1 = primary inputs are fp32
__device__ inline float rdv(const void* p, size_t i, int f32) {
  return f32 ? ((const float*)p)[i] : __bfloat162float(((const bf16*)p)[i]);
}

__device__ inline int4 pack8(const float* s) {   // 8 fp32 -> 8 bf16 (RNE)
  unsigned short h[8];
#pragma unroll
  for (int t = 0; t < 8; t++) {
    bf16 b = __float2bfloat16(s[t]);
    __builtin_memcpy(&h[t], &b, 2);
  }
  int4 r;
  r.x = (int)((unsigned)h[0] | ((unsigned)h[1] << 16));
  r.y = (int)((unsigned)h[2] | ((unsigned)h[3] << 16));
  r.z = (int)((unsigned)h[4] | ((unsigned)h[5] << 16));
  r.w = (int)((unsigned)h[6] | ((unsigned)h[7] << 16));
  return r;
}

// async global->LDS, 16B per lane; LDS dest = wave-uniform base + lane*16
typedef __attribute__((address_space(1))) const unsigned int gu32;
typedef __attribute__((address_space(3))) unsigned int lu32;
__device__ __forceinline__ void gload16(const void* g, void* l) {
  __builtin_amdgcn_global_load_lds((gu32*)g, (lu32*)l, 16, 0, 0);
}

// -------- dtype detector --------
__global__ __launch_bounds__(256) void detect_dtype(const unsigned short* __restrict__ x,
                                                    int* __restrict__ flag) {
  int tid = threadIdx.x;
  int cnt = 0;
#pragma unroll
  for (int i = 0; i < 4; i++) {
    unsigned short u = x[tid * 4 + i];
    int e = (u >> 7) & 0xFF;
    cnt += (e >= 118 && e <= 130) ? 1 : 0;
  }
#pragma unroll
  for (int off = 1; off < 64; off <<= 1) cnt += __shfl_xor(cnt, off);
  __shared__ int red[4];
  if ((tid & 63) == 0) red[tid >> 6] = cnt;
  __syncthreads();
  if (tid == 0) flag[0] = ((red[0] + red[1] + red[2] + red[3]) > 768) ? 0 : 1;
}

__global__ __launch_bounds__(256) void sentinel_kernel(bf16* out, int n) {
  int i = blockIdx.x * 256 + threadIdx.x;
  if (i < n) out[i] = __float2bfloat16(1000.0f);
}

// ---------------- GEMM 128x128: C[M,N] = A[M,K] @ W[N,K]^T + bias[N] --------
// Staging: global_load_lds 16B, XOR-swizzled cols (c ^ (row>>1)&3), no pad.
// M, N must be multiples of 128. OMODE: 0=f32 out, 1=bf16 out, 2=flag dtype.
template<int OMODE, bool A_DYN>
__global__ __launch_bounds__(256) void gemm128(
    const void* __restrict__ A, const void* __restrict__ W,
    const void* __restrict__ bias, void* __restrict__ Cout,
    int M, int N, int K, const int* __restrict__ flagp)
{
  const int f32in = flagp[0];
  __shared__ int4 As4[128 * 4];
  __shared__ int4 Bs4[128 * 4];
  const int tid = threadIdx.x, lane = tid & 63, wave = tid >> 6;
  const int grp = lane >> 4, l16 = lane & 15;
  const int m0 = blockIdx.x * 128, n0 = blockIdx.y * 128;
  const int wm = (wave & 1) * 64, wn = (wave >> 1) * 64;
  float4x acc[4][4] = {};
  for (int k0 = 0; k0 < K; k0 += 32) {
    if (!f32in) {
#pragma unroll
      for (int j = 0; j < 2; j++) {
        int row = wave * 32 + j * 16 + (lane >> 2);
        int cs = (lane & 3) ^ ((row >> 1) & 3);
        gload16((const bf16*)A + (size_t)(m0 + row) * K + k0 + cs * 8,
                &As4[(wave * 32 + j * 16) * 4]);
        gload16((const bf16*)W + (size_t)(n0 + row) * K + k0 + cs * 8,
                &Bs4[(wave * 32 + j * 16) * 4]);
      }
    } else {
#pragma unroll
      for (int i = 0; i < 2; i++) {
        int ch = tid + i * 256;          // 512 chunks per matrix
        int row = ch >> 2, c = ch & 3;
        int cs = c ^ ((row >> 1) & 3);
        size_t aoff = (size_t)(m0 + row) * K + k0 + cs * 8;
        size_t boff = (size_t)(n0 + row) * K + k0 + cs * 8;
        As4[row * 4 + c] = A_DYN ? pack8((const float*)A + aoff)
                                 : *(const int4*)((const bf16*)A + aoff);
        Bs4[row * 4 + c] = pack8((const float*)W + boff);
      }
    }
    __syncthreads();    // drains vmcnt (incl. global_load_lds) before use
    short8x af[4], bfr[4];
#pragma unroll
    for (int i = 0; i < 4; i++) {
      int ra = wm + i * 16 + l16;
      int rb = wn + i * 16 + l16;
      af[i]  = *(const short8x*)&As4[ra * 4 + (grp ^ ((ra >> 1) & 3))];
      bfr[i] = *(const short8x*)&Bs4[rb * 4 + (grp ^ ((rb >> 1) & 3))];
    }
#pragma unroll
    for (int i = 0; i < 4; i++)
#pragma unroll
      for (int j = 0; j < 4; j++)
        acc[i][j] = __builtin_amdgcn_mfma_f32_16x16x32_bf16(af[i], bfr[j], acc[i][j], 0, 0, 0);
    __syncthreads();
  }
  // D layout: col=lane&15, row=(lane>>4)*4+r
#pragma unroll
  for (int j = 0; j < 4; j++) {
    int gn = n0 + wn + j * 16 + l16;
    float bv = rdv(bias, gn, f32in);
#pragma unroll
    for (int i = 0; i < 4; i++) {
      int gm0 = m0 + wm + i * 16 + grp * 4;
#pragma unroll
      for (int r = 0; r < 4; r++) {
        float v = acc[i][j][r] + bv;
        size_t idx = (size_t)(gm0 + r) * N + gn;
        if (OMODE == 0)      ((float*)Cout)[idx] = v;
        else if (OMODE == 1) ((bf16*)Cout)[idx] = __float2bfloat16(v);
        else {
          if (f32in) ((float*)Cout)[idx] = v;
          else       ((bf16*)Cout)[idx] = __float2bfloat16(v);
        }
      }
    }
  }
}

// ---------------- GEMM 64x64 (small-N shapes; 4x the blocks of 128x128) -----
template<int OMODE, bool A_DYN>
__global__ __launch_bounds__(256) void gemm64(
    const void* __restrict__ A, const void* __restrict__ W,
    const void* __restrict__ bias, void* __restrict__ Cout,
    int M, int N, int K, const int* __restrict__ flagp)
{
  const int f32in = flagp[0];
  __shared__ int4 As4[64 * 4];
  __shared__ int4 Bs4[64 * 4];
  const int tid = threadIdx.x, lane = tid & 63, wave = tid >> 6;
  const int grp = lane >> 4, l16 = lane & 15;
  const int m0 = blockIdx.x * 64, n0 = blockIdx.y * 64;
  const int wm = (wave & 1) * 32, wn = (wave >> 1) * 32;
  float4x acc[2][2] = {};
  for (int k0 = 0; k0 < K; k0 += 32) {
    if (!f32in) {
      int row = wave * 16 + (lane >> 2);
      int cs = (lane & 3) ^ ((row >> 1) & 3);
      gload16((const bf16*)A + (size_t)(m0 + row) * K + k0 + cs * 8,
              &As4[wave * 16 * 4]);
      gload16((const bf16*)W + (size_t)(n0 + row) * K + k0 + cs * 8,
              &Bs4[wave * 16 * 4]);
    } else {
      int row = tid >> 2, c = tid & 3;        // 256 chunks per matrix
      int cs = c ^ ((row >> 1) & 3);
      size_t aoff = (size_t)(m0 + row) * K + k0 + cs * 8;
      size_t boff = (size_t)(n0 + row) * K + k0 + cs * 8;
      As4[row * 4 + c] = A_DYN ? pack8((const float*)A + aoff)
                               : *(const int4*)((const bf16*)A + aoff);
      Bs4[row * 4 + c] = pack8((const float*)W + boff);
    }
    __syncthreads();
    short8x af[2], bfr[2];
#pragma unroll
    for (int i = 0; i < 2; i++) {
      int ra = wm + i * 16 + l16;
      int rb = wn + i * 16 + l16;
      af[i]  = *(const short8x*)&As4[ra * 4 + (grp ^ ((ra >> 1) & 3))];
      bfr[i] = *(const short8x*)&Bs4[rb * 4 + (grp ^ ((rb >> 1) & 3))];
    }
#pragma unroll
    for (int i = 0; i < 2; i++)
#pragma unroll
      for (int j = 0; j < 2; j++)
        acc[i][j] = __builtin_amdgcn_mfma_f32_16x16x32_bf16(af[i], bfr[j], acc[i][j], 0, 0, 0);
    __syncthreads();
  }
#pragma unroll
  for (int j = 0; j < 2; j++) {
    int gn = n0 + wn + j * 16 + l16;
    float bv = rdv(bias, gn, f32in);
#pragma unroll
    for (int i = 0; i < 2; i++) {
      int gm0 = m0 + wm + i * 16 + grp * 4;
#pragma unroll
      for (int r = 0; r < 4; r++) {
        float v = acc[i][j][r] + bv;
        size_t idx = (size_t)(gm0 + r) * N + gn;
        if (OMODE == 0)      ((float*)Cout)[idx] = v;
        else if (OMODE == 1) ((bf16*)Cout)[idx] = __float2bfloat16(v);
        else {
          if (f32in) ((float*)Cout)[idx] = v;
          else       ((bf16*)Cout)[idx] = __float2bfloat16(v);
        }
      }
    }
  }
}

// ---------------- RMSNorm over 512 fp32 -> bf16 ----------------
__global__ __launch_bounds__(256) void rmsnorm512(
    const float* __restrict__ in, const void* __restrict__ w,
    bf16* __restrict__ out, const int* __restrict__ flagp)
{
  const int f32in = flagp[0];
  const int s = blockIdx.x, tid = threadIdx.x;
  const float* row = in + (size_t)s * 512;
  float v0 = row[tid], v1 = row[tid + 256];
  float ss = v0 * v0 + v1 * v1;
#pragma unroll
  for (int off = 1; off < 64; off <<= 1) ss += __shfl_xor(ss, off);
  __shared__ float red[4];
  if ((tid & 63) == 0) red[tid >> 6] = ss;
  __syncthreads();
  float tot = red[0] + red[1] + red[2] + red[3];
  float scale = rsqrtf(tot * (1.0f / 512.0f) + EPS_F);
  out[(size_t)s * 512 + tid]       = __float2bfloat16(v0 * scale * rdv(w, tid, f32in));
  out[(size_t)s * 512 + tid + 256] = __float2bfloat16(v1 * scale * rdv(w, tid + 256, f32in));
}

// ---------------- kv_a post: rmsnorm(512) + rope(last 64) ----------------
__global__ __launch_bounds__(256) void kv_post(
    const float* __restrict__ kv, const void* __restrict__ w,
    const void* __restrict__ cosb, const void* __restrict__ sinb,
    bf16* __restrict__ kvn, bf16* __restrict__ kpe, const int* __restrict__ flagp)
{
  const int f32in = flagp[0];
  const int s = blockIdx.x, tid = threadIdx.x;
  const float* row = kv + (size_t)s * 576;
  float v0 = row[tid], v1 = row[tid + 256];
  float ss = v0 * v0 + v1 * v1;
#pragma unroll
  for (int off = 1; off < 64; off <<= 1) ss += __shfl_xor(ss, off);
  __shared__ float red[4];
  if ((tid & 63) == 0) red[tid >> 6] = ss;
  __syncthreads();
  float tot = red[0] + red[1] + red[2] + red[3];
  float scale = rsqrtf(tot * (1.0f / 512.0f) + EPS_F);
  kvn[(size_t)s * 512 + tid]       = __float2bfloat16(v0 * scale * rdv(w, tid, f32in));
  kvn[(size_t)s * 512 + tid + 256] = __float2bfloat16(v1 * scale * rdv(w, tid + 256, f32in));
  if (tid < 32) {
    float x0 = row[512 + 2 * tid], x1 = row[512 + 2 * tid + 1];
    float c  = rdv(cosb, (size_t)s * 32 + tid, f32in);
    float sn = rdv(sinb, (size_t)s * 32 + tid, f32in);
    kpe[s * 64 + 2 * tid]     = __float2bfloat16(x0 * c - x1 * sn);
    kpe[s * 64 + 2 * tid + 1] = __float2bfloat16(x0 * sn + x1 * c);
  }
}

// ---------------- in-place rope on q (S,3072): d in [128,192) of each head ----
__global__ __launch_bounds__(256) void rope_q_inplace(
    bf16* __restrict__ q, const void* __restrict__ cosb,
    const void* __restrict__ sinb, const int* __restrict__ flagp)
{
  const int f32in = flagp[0];
  const int s = blockIdx.x, tid = threadIdx.x;
#pragma unroll
  for (int it = 0; it < 2; it++) {
    int p = tid + it * 256;                 // rope pair index (16 heads x 32)
    int hh = p >> 5, jj = p & 31;
    bf16* src = q + (size_t)s * 3072 + hh * 192 + 128 + 2 * jj;
    float x0 = __bfloat162float(src[0]);
    float x1 = __bfloat162float(src[1]);
    float c  = rdv(cosb, (size_t)s * 32 + jj, f32in);
    float sn = rdv(sinb, (size_t)s * 32 + jj, f32in);
    src[0] = __float2bfloat16(x0 * c - x1 * sn);
    src[1] = __float2bfloat16(x0 * sn + x1 * c);
  }
}

// ---------------- Vt (H,128,S) = transpose of v part of kvb ----------------
__global__ __launch_bounds__(256) void build_vt(
    const bf16* __restrict__ kvb, bf16* __restrict__ Vt)
{
  __shared__ __align__(16) bf16 tile[64][136];
  const int h = blockIdx.x;
  const int t0 = blockIdx.y * 64;
  const int tid = threadIdx.x;
#pragma unroll
  for (int i = 0; i < 4; i++) {
    int chunk = tid + i * 256;          // 1024 chunks of 8 bf16
    int row = chunk >> 4;
    int c8 = (chunk & 15) * 8;
    *(int4*)&tile[row][c8] =
        *(const int4*)(kvb + (size_t)(t0 + row) * 4096 + h * 256 + 128 + c8);
  }
  __syncthreads();
#pragma unroll
  for (int i = 0; i < 32; i++) {
    int idx = tid + i * 256;            // 8192 elems
    int d = idx >> 6;
    int t = idx & 63;
    Vt[((size_t)h * 128 + d) * 2048 + t0 + t] = tile[t][d];
  }
}

// ---------------- flash attention (round-3 body; flat-grid swizzle only) ----
// Flat grid 512; block b -> head b&15, q-tile t=(b>>4)&15 for b<256 else 31-t.
// Bijective relabel of independent blocks; correctness independent of dispatch.
__global__ __launch_bounds__(256) void attn_kernel(
    const bf16* __restrict__ Q, const bf16* __restrict__ kvb,
    const bf16* __restrict__ kpe, const bf16* __restrict__ Vt,
    bf16* __restrict__ Out)
{
  __shared__ __align__(16) bf16 Ks[64 * 200];      // 64 rows x 192, pad->200
  __shared__ __align__(16) bf16 Vs[128 * 72];      // 128 d-rows x 64, pad->72
  __shared__ __align__(16) bf16 plds[4][16 * 68];  // per-wave P 16x64, stride 68
  const int b = blockIdx.x;
  const int h = b & 15;
  const int tt = (b >> 4) & 15;
  const int q0 = ((b >> 8) ? (31 - tt) : tt) * 64;
  const int tid = threadIdx.x;
  const int wave = tid >> 6;
  const int lane = tid & 63;
  const int grp = lane >> 4, l16 = lane & 15;
  const int qrt = q0 + wave * 16;
  const bf16* Qbase = Q + (size_t)(qrt + l16) * 3072 + h * 192;
  short8x qf[6];                                   // Q fragments, loaded once
#pragma unroll
  for (int c = 0; c < 6; c++)
    qf[c] = *(const short8x*)(Qbase + c * 32 + grp * 8);
  float m_run[4], l_run[4];
  float4x o_acc[8] = {};
#pragma unroll
  for (int r = 0; r < 4; r++) { m_run[r] = -__builtin_inff(); l_run[r] = 0.f; }
  bf16* pl = &plds[wave][0];
  for (int t0 = 0; t0 <= q0; t0 += 64) {
    // ---- cooperative stage: K nope (64x128), K rope (64x64), V (128x64) ----
#pragma unroll
    for (int i = 0; i < 4; i++) {
      int ch = tid + i * 256;                      // 1024 int4
      int row = ch >> 4, c = ch & 15;
      *(int4*)&Ks[row * 200 + c * 8] =
          *(const int4*)(kvb + (size_t)(t0 + row) * 4096 + h * 256 + c * 8);
    }
#pragma unroll
    for (int i = 0; i < 2; i++) {
      int ch = tid + i * 256;                      // 512 int4
      int row = ch >> 3, c = ch & 7;
      *(int4*)&Ks[row * 200 + 128 + c * 8] =
          *(const int4*)(kpe + (size_t)(t0 + row) * 64 + c * 8);
    }
#pragma unroll
    for (int i = 0; i < 4; i++) {
      int ch = tid + i * 256;                      // 1024 int4
      int row = ch >> 3, c = ch & 7;
      *(int4*)&Vs[row * 72 + c * 8] =
          *(const int4*)(Vt + ((size_t)h * 128 + row) * 2048 + t0 + c * 8);
    }
    __syncthreads();
    // ---- S = Q K^T (fragments from LDS) ----
    float4x sacc[4] = {};
#pragma unroll
    for (int n = 0; n < 4; n++) {
      const bf16* Kb = &Ks[(n * 16 + l16) * 200 + grp * 8];
#pragma unroll
      for (int c = 0; c < 6; c++) {
        short8x kf = *(const short8x*)(Kb + c * 32);
        sacc[n] = __builtin_amdgcn_mfma_f32_16x16x32_bf16(qf[c], kf, sacc[n], 0, 0, 0);
      }
    }
    // ---- scale + causal mask + online softmax ----
    float pv[4][4], alpha[4];
#pragma unroll
    for (int r = 0; r < 4; r++) {
      const int s_row = qrt + grp * 4 + r;
      float p0[4];
      float mx = -__builtin_inff();
#pragma unroll
      for (int n = 0; n < 4; n++) {
        int t = t0 + n * 16 + l16;
        float v = sacc[n][r] * SCALE_F;
        v = (t > s_row) ? -1.0e9f : v;
        p0[n] = v;
        mx = fmaxf(mx, v);
      }
      mx = fmaxf(mx, __shfl_xor(mx, 1));
      mx = fmaxf(mx, __shfl_xor(mx, 2));
      mx = fmaxf(mx, __shfl_xor(mx, 4));
      mx = fmaxf(mx, __shfl_xor(mx, 8));
      float m_new = fmaxf(m_run[r], mx);
      float a = __expf(m_run[r] - m_new);
      m_run[r] = m_new;
      float sum = 0.f;
#pragma unroll
      for (int n = 0; n < 4; n++) {
        float e = __expf(p0[n] - m_new);
        pv[n][r] = e;
        sum += e;
      }
      sum += __shfl_xor(sum, 1);
      sum += __shfl_xor(sum, 2);
      sum += __shfl_xor(sum, 4);
      sum += __shfl_xor(sum, 8);
      l_run[r] = l_run[r] * a + sum;
      alpha[r] = a;
    }
#pragma unroll
    for (int n = 0; n < 8; n++)
#pragma unroll
      for (int r = 0; r < 4; r++)
        o_acc[n][r] *= alpha[r];
    // ---- P: D-layout -> per-wave LDS -> A-layout ----
#pragma unroll
    for (int n = 0; n < 4; n++)
#pragma unroll
      for (int r = 0; r < 4; r++)
        pl[(grp * 4 + r) * 68 + n * 16 + l16] = __float2bfloat16(pv[n][r]);
#pragma unroll
    for (int c = 0; c < 2; c++) {
      union { short4x h4[2]; short8x v8; } pk;
      const bf16* pp = pl + l16 * 68 + c * 32 + grp * 8;
      pk.h4[0] = *(const short4x*)(pp);
      pk.h4[1] = *(const short4x*)(pp + 4);
#pragma unroll
      for (int n = 0; n < 8; n++) {
        short8x vf = *(const short8x*)&Vs[(size_t)(n * 16 + l16) * 72 + c * 32 + grp * 8];
        o_acc[n] = __builtin_amdgcn_mfma_f32_16x16x32_bf16(pk.v8, vf, o_acc[n], 0, 0, 0);
      }
    }
    __syncthreads();
  }
  float inv[4];
#pragma unroll
  for (int r = 0; r < 4; r++) inv[r] = 1.0f / l_run[r];
#pragma unroll
  for (int n = 0; n < 8; n++)
#pragma unroll
    for (int r = 0; r < 4; r++) {
      int s_row = qrt + grp * 4 + r;
      Out[(size_t)s_row * 2048 + h * 128 + n * 16 + l16] =
          __float2bfloat16(o_acc[n][r] * inv[r]);
    }
}

extern "C" void kernel_launch(void* const* d_in, const int* in_sizes, int n_in,
                              void* d_out, int out_size, void* d_ws, size_t ws_size,
                              hipStream_t stream) {
  const void* x        = d_in[0];
  const void* fcos     = d_in[2];
  const void* fsin     = d_in[3];
  const void* wq_a_w   = d_in[5];
  const void* wq_a_b   = d_in[6];
  const void* q_norm_w = d_in[7];
  const void* wq_b_w   = d_in[8];
  const void* wq_b_b   = d_in[9];
  const void* wkv_a_w  = d_in[10];
  const void* wkv_a_b  = d_in[11];
  const void* kv_norm_w= d_in[12];
  const void* wkv_b_w  = d_in[13];
  const void* wkv_b_b  = d_in[14];
  const void* wo_w     = d_in[15];
  const void* wo_b     = d_in[16];

  const size_t MB = 1024 * 1024;
  if (ws_size < 46 * MB) {   // diagnostic: absmax ~1000 => ws too small
    sentinel_kernel<<<(out_size + 255) / 256, 256, 0, stream>>>((bf16*)d_out, out_size);
    return;
  }
  char* ws = (char*)d_ws;
  // round-3 exact region plan (known good):
  int*   flag   = (int*)(ws);                      // [0, 4B)
  float* q_a    = (float*)(ws + 1 * MB);           // [1,5)   fp32 2048x512
  bf16*  qn     = (bf16*)(ws + 5 * MB);            // [5,7)
  float* kv_a   = (float*)(ws + 1 * MB);           // [1,5.5) fp32 2048x576 (q_a/qn dead)
  bf16*  kvn    = (bf16*)(ws + 6 * MB);            // [6,8)
  bf16*  attnout= (bf16*)(ws + 1 * MB);            // [1,9)   (kv_a/kvn dead)
  bf16*  qbuf   = (bf16*)(ws + 9 * MB);            // [9,21)  2048x3072, roped in place
  bf16*  kvb    = (bf16*)(ws + 21 * MB);           // [21,37) 2048x4096
  bf16*  Vt     = (bf16*)(ws + 37 * MB);           // [37,45) 16x128x2048
  bf16*  kpe    = (bf16*)(ws + 45 * MB);           // [45,45.25) 2048x64

  dim3 blk(256);
  detect_dtype<<<1, blk, 0, stream>>>((const unsigned short*)x, flag);
  // Q branch
  gemm64 <0, true ><<<dim3(32,  8), blk, 0, stream>>>(x,   wq_a_w,  wq_a_b,  q_a,  2048,  512, 2048, flag);
  rmsnorm512<<<2048, blk, 0, stream>>>(q_a, q_norm_w, qn, flag);
  gemm128<1, false><<<dim3(16, 24), blk, 0, stream>>>(qn,  wq_b_w,  wq_b_b,  qbuf, 2048, 3072,  512, flag);
  rope_q_inplace<<<2048, blk, 0, stream>>>(qbuf, fcos, fsin, flag);
  // KV branch
  gemm64 <0, true ><<<dim3(32,  9), blk, 0, stream>>>(x,   wkv_a_w, wkv_a_b, kv_a, 2048,  576, 2048, flag);
  kv_post<<<2048, blk, 0, stream>>>(kv_a, kv_norm_w, fcos, fsin, kvn, kpe, flag);
  gemm128<1, false><<<dim3(16, 32), blk, 0, stream>>>(kvn, wkv_b_w, wkv_b_b, kvb,  2048, 4096,  512, flag);
  build_vt<<<dim3(16, 32), blk, 0, stream>>>(kvb, Vt);
  // Attention + output projection
  attn_kernel<<<dim3(512), blk, 0, stream>>>(qbuf, kvb, kpe, Vt, attnout);
  gemm128<2, false><<<dim3(16, 16), blk, 0, stream>>>(attnout, wo_w, wo_b, d_out, 2048, 2048, 2048, flag);
}

// Round 8
// 384.328 us; speedup vs baseline: 2.1053x; 1.1318x over previous
//
#include <hip/hip_runtime.h>
#include <hip/hip_bf16.h>

typedef __attribute__((ext_vector_type(8))) short short8x;  // 8 bf16 = 4 VGPR
typedef __attribute__((ext_vector_type(4))) short short4x;  // 8B
typedef __attribute__((ext_vector_type(4))) float float4x;  // MFMA C/D
typedef __hip_bfloat16 bf16;

#define EPS_F 1.1920929e-07f
#define SCALE_F 0.07216878364870323f   // 192^-0.5

// flag semantics: 0 = primary inputs are bf16, 1 = primary inputs are fp32
__device__ inline float rdv(const void* p, size_t i, int f32) {
  return f32 ? ((const float*)p)[i] : __bfloat162float(((const bf16*)p)[i]);
}

__device__ inline int4 pack8(const float* s) {   // 8 fp32 -> 8 bf16 (RNE)
  unsigned short h[8];
#pragma unroll
  for (int t = 0; t < 8; t++) {
    bf16 b = __float2bfloat16(s[t]);
    __builtin_memcpy(&h[t], &b, 2);
  }
  int4 r;
  r.x = (int)((unsigned)h[0] | ((unsigned)h[1] << 16));
  r.y = (int)((unsigned)h[2] | ((unsigned)h[3] << 16));
  r.z = (int)((unsigned)h[4] | ((unsigned)h[5] << 16));
  r.w = (int)((unsigned)h[6] | ((unsigned)h[7] << 16));
  return r;
}

// async global->LDS, 16B per lane; LDS dest = wave-uniform base + lane*16
typedef __attribute__((address_space(1))) const unsigned int gu32;
typedef __attribute__((address_space(3))) unsigned int lu32;
__device__ __forceinline__ void gload16(const void* g, void* l) {
  __builtin_amdgcn_global_load_lds((gu32*)g, (lu32*)l, 16, 0, 0);
}

// -------- dtype detector --------
__global__ __launch_bounds__(256) void detect_dtype(const unsigned short* __restrict__ x,
                                                    int* __restrict__ flag) {
  int tid = threadIdx.x;
  int cnt = 0;
#pragma unroll
  for (int i = 0; i < 4; i++) {
    unsigned short u = x[tid * 4 + i];
    int e = (u >> 7) & 0xFF;
    cnt += (e >= 118 && e <= 130) ? 1 : 0;
  }
#pragma unroll
  for (int off = 1; off < 64; off <<= 1) cnt += __shfl_xor(cnt, off);
  __shared__ int red[4];
  if ((tid & 63) == 0) red[tid >> 6] = cnt;
  __syncthreads();
  if (tid == 0) flag[0] = ((red[0] + red[1] + red[2] + red[3]) > 768) ? 0 : 1;
}

__global__ __launch_bounds__(256) void sentinel_kernel(bf16* out, int n) {
  int i = blockIdx.x * 256 + threadIdx.x;
  if (i < n) out[i] = __float2bfloat16(1000.0f);
}

// ---------------- GEMM 128x128 body (verbatim round-7 logic) ----------------
template<int OMODE, bool A_DYN>
__device__ __forceinline__ void gemm128_body(
    const void* __restrict__ A, const void* __restrict__ W,
    const void* __restrict__ bias, void* __restrict__ Cout,
    int M, int N, int K, int f32in, int bx, int by)
{
  __shared__ int4 As4[128 * 4];
  __shared__ int4 Bs4[128 * 4];
  const int tid = threadIdx.x, lane = tid & 63, wave = tid >> 6;
  const int grp = lane >> 4, l16 = lane & 15;
  const int m0 = bx * 128, n0 = by * 128;
  const int wm = (wave & 1) * 64, wn = (wave >> 1) * 64;
  float4x acc[4][4] = {};
  for (int k0 = 0; k0 < K; k0 += 32) {
    if (!f32in) {
#pragma unroll
      for (int j = 0; j < 2; j++) {
        int row = wave * 32 + j * 16 + (lane >> 2);
        int cs = (lane & 3) ^ ((row >> 1) & 3);
        gload16((const bf16*)A + (size_t)(m0 + row) * K + k0 + cs * 8,
                &As4[(wave * 32 + j * 16) * 4]);
        gload16((const bf16*)W + (size_t)(n0 + row) * K + k0 + cs * 8,
                &Bs4[(wave * 32 + j * 16) * 4]);
      }
    } else {
#pragma unroll
      for (int i = 0; i < 2; i++) {
        int ch = tid + i * 256;
        int row = ch >> 2, c = ch & 3;
        int cs = c ^ ((row >> 1) & 3);
        size_t aoff = (size_t)(m0 + row) * K + k0 + cs * 8;
        size_t boff = (size_t)(n0 + row) * K + k0 + cs * 8;
        As4[row * 4 + c] = A_DYN ? pack8((const float*)A + aoff)
                                 : *(const int4*)((const bf16*)A + aoff);
        Bs4[row * 4 + c] = pack8((const float*)W + boff);
      }
    }
    __syncthreads();
    short8x af[4], bfr[4];
#pragma unroll
    for (int i = 0; i < 4; i++) {
      int ra = wm + i * 16 + l16;
      int rb = wn + i * 16 + l16;
      af[i]  = *(const short8x*)&As4[ra * 4 + (grp ^ ((ra >> 1) & 3))];
      bfr[i] = *(const short8x*)&Bs4[rb * 4 + (grp ^ ((rb >> 1) & 3))];
    }
#pragma unroll
    for (int i = 0; i < 4; i++)
#pragma unroll
      for (int j = 0; j < 4; j++)
        acc[i][j] = __builtin_amdgcn_mfma_f32_16x16x32_bf16(af[i], bfr[j], acc[i][j], 0, 0, 0);
    __syncthreads();
  }
#pragma unroll
  for (int j = 0; j < 4; j++) {
    int gn = n0 + wn + j * 16 + l16;
    float bv = rdv(bias, gn, f32in);
#pragma unroll
    for (int i = 0; i < 4; i++) {
      int gm0 = m0 + wm + i * 16 + grp * 4;
#pragma unroll
      for (int r = 0; r < 4; r++) {
        float v = acc[i][j][r] + bv;
        size_t idx = (size_t)(gm0 + r) * N + gn;
        if (OMODE == 0)      ((float*)Cout)[idx] = v;
        else if (OMODE == 1) ((bf16*)Cout)[idx] = __float2bfloat16(v);
        else {
          if (f32in) ((float*)Cout)[idx] = v;
          else       ((bf16*)Cout)[idx] = __float2bfloat16(v);
        }
      }
    }
  }
}

template<int OMODE, bool A_DYN>
__global__ __launch_bounds__(256) void gemm128(
    const void* __restrict__ A, const void* __restrict__ W,
    const void* __restrict__ bias, void* __restrict__ Cout,
    int M, int N, int K, const int* __restrict__ flagp)
{
  gemm128_body<OMODE, A_DYN>(A, W, bias, Cout, M, N, K, flagp[0],
                             blockIdx.x, blockIdx.y);
}

// q_b and kv_b in one dispatch: z=0 -> (qn,wq_b)->qbuf N=3072 (24 tiles);
// z=1 -> (kvn,wkv_b)->kvb N=4096 (32 tiles). Grid (16,32,2).
__global__ __launch_bounds__(256) void gemmB_dual(
    const void* __restrict__ A0, const void* __restrict__ A1,
    const void* __restrict__ W0, const void* __restrict__ W1,
    const void* __restrict__ b0, const void* __restrict__ b1,
    void* __restrict__ C0, void* __restrict__ C1,
    const int* __restrict__ flagp)
{
  const int z = blockIdx.z;
  if (z == 0 && blockIdx.y >= 24) return;
  const void* A = z ? A1 : A0;
  const void* W = z ? W1 : W0;
  const void* bias = z ? b1 : b0;
  void* C = z ? C1 : C0;
  const int N = z ? 4096 : 3072;
  gemm128_body<1, false>(A, W, bias, C, 2048, N, 512, flagp[0],
                         blockIdx.x, blockIdx.y);
}

// ---------------- GEMM 64x64 body (verbatim round-7 logic) ----------------
template<int OMODE, bool A_DYN>
__device__ __forceinline__ void gemm64_body(
    const void* __restrict__ A, const void* __restrict__ W,
    const void* __restrict__ bias, void* __restrict__ Cout,
    int M, int N, int K, int f32in, int bx, int by)
{
  __shared__ int4 As4[64 * 4];
  __shared__ int4 Bs4[64 * 4];
  const int tid = threadIdx.x, lane = tid & 63, wave = tid >> 6;
  const int grp = lane >> 4, l16 = lane & 15;
  const int m0 = bx * 64, n0 = by * 64;
  const int wm = (wave & 1) * 32, wn = (wave >> 1) * 32;
  float4x acc[2][2] = {};
  for (int k0 = 0; k0 < K; k0 += 32) {
    if (!f32in) {
      int row = wave * 16 + (lane >> 2);
      int cs = (lane & 3) ^ ((row >> 1) & 3);
      gload16((const bf16*)A + (size_t)(m0 + row) * K + k0 + cs * 8,
              &As4[wave * 16 * 4]);
      gload16((const bf16*)W + (size_t)(n0 + row) * K + k0 + cs * 8,
              &Bs4[wave * 16 * 4]);
    } else {
      int row = tid >> 2, c = tid & 3;
      int cs = c ^ ((row >> 1) & 3);
      size_t aoff = (size_t)(m0 + row) * K + k0 + cs * 8;
      size_t boff = (size_t)(n0 + row) * K + k0 + cs * 8;
      As4[row * 4 + c] = A_DYN ? pack8((const float*)A + aoff)
                               : *(const int4*)((const bf16*)A + aoff);
      Bs4[row * 4 + c] = pack8((const float*)W + boff);
    }
    __syncthreads();
    short8x af[2], bfr[2];
#pragma unroll
    for (int i = 0; i < 2; i++) {
      int ra = wm + i * 16 + l16;
      int rb = wn + i * 16 + l16;
      af[i]  = *(const short8x*)&As4[ra * 4 + (grp ^ ((ra >> 1) & 3))];
      bfr[i] = *(const short8x*)&Bs4[rb * 4 + (grp ^ ((rb >> 1) & 3))];
    }
#pragma unroll
    for (int i = 0; i < 2; i++)
#pragma unroll
      for (int j = 0; j < 2; j++)
        acc[i][j] = __builtin_amdgcn_mfma_f32_16x16x32_bf16(af[i], bfr[j], acc[i][j], 0, 0, 0);
    __syncthreads();
  }
#pragma unroll
  for (int j = 0; j < 2; j++) {
    int gn = n0 + wn + j * 16 + l16;
    float bv = rdv(bias, gn, f32in);
#pragma unroll
    for (int i = 0; i < 2; i++) {
      int gm0 = m0 + wm + i * 16 + grp * 4;
#pragma unroll
      for (int r = 0; r < 4; r++) {
        float v = acc[i][j][r] + bv;
        size_t idx = (size_t)(gm0 + r) * N + gn;
        if (OMODE == 0)      ((float*)Cout)[idx] = v;
        else if (OMODE == 1) ((bf16*)Cout)[idx] = __float2bfloat16(v);
        else {
          if (f32in) ((float*)Cout)[idx] = v;
          else       ((bf16*)Cout)[idx] = __float2bfloat16(v);
        }
      }
    }
  }
}

// q_a and kv_a in one dispatch: z=0 -> x@wq_a^T -> q_a f32, N=512 (8 tiles);
// z=1 -> x@wkv_a^T -> kv_a f32, N=576 (9 tiles). Grid (32,9,2).
__global__ __launch_bounds__(256) void gemmA_dual(
    const void* __restrict__ A,
    const void* __restrict__ W0, const void* __restrict__ W1,
    const void* __restrict__ b0, const void* __restrict__ b1,
    float* __restrict__ C0, float* __restrict__ C1,
    const int* __restrict__ flagp)
{
  const int z = blockIdx.z;
  const int N = z ? 576 : 512;
  if (blockIdx.y * 64 >= N) return;
  const void* W = z ? W1 : W0;
  const void* bias = z ? b1 : b0;
  float* C = z ? C1 : C0;
  gemm64_body<0, true>(A, W, bias, C, 2048, N, 2048, flagp[0],
                       blockIdx.x, blockIdx.y);
}

// ------ merged norms: b<2048 -> rmsnorm512 on q_a; else kv_post on kv_a -----
__global__ __launch_bounds__(256) void norms_merged(
    const float* __restrict__ q_a, const float* __restrict__ kv_a,
    const void* __restrict__ qw, const void* __restrict__ kvw,
    const void* __restrict__ cosb, const void* __restrict__ sinb,
    bf16* __restrict__ qn, bf16* __restrict__ kvn, bf16* __restrict__ kpe,
    const int* __restrict__ flagp)
{
  const int f32in = flagp[0];
  const int b = blockIdx.x, tid = threadIdx.x;
  __shared__ float red[4];
  if (b < 2048) {
    const int s = b;
    const float* row = q_a + (size_t)s * 512;
    float v0 = row[tid], v1 = row[tid + 256];
    float ss = v0 * v0 + v1 * v1;
#pragma unroll
    for (int off = 1; off < 64; off <<= 1) ss += __shfl_xor(ss, off);
    if ((tid & 63) == 0) red[tid >> 6] = ss;
    __syncthreads();
    float tot = red[0] + red[1] + red[2] + red[3];
    float scale = rsqrtf(tot * (1.0f / 512.0f) + EPS_F);
    qn[(size_t)s * 512 + tid]       = __float2bfloat16(v0 * scale * rdv(qw, tid, f32in));
    qn[(size_t)s * 512 + tid + 256] = __float2bfloat16(v1 * scale * rdv(qw, tid + 256, f32in));
  } else {
    const int s = b - 2048;
    const float* row = kv_a + (size_t)s * 576;
    float v0 = row[tid], v1 = row[tid + 256];
    float ss = v0 * v0 + v1 * v1;
#pragma unroll
    for (int off = 1; off < 64; off <<= 1) ss += __shfl_xor(ss, off);
    if ((tid & 63) == 0) red[tid >> 6] = ss;
    __syncthreads();
    float tot = red[0] + red[1] + red[2] + red[3];
    float scale = rsqrtf(tot * (1.0f / 512.0f) + EPS_F);
    kvn[(size_t)s * 512 + tid]       = __float2bfloat16(v0 * scale * rdv(kvw, tid, f32in));
    kvn[(size_t)s * 512 + tid + 256] = __float2bfloat16(v1 * scale * rdv(kvw, tid + 256, f32in));
    if (tid < 32) {
      float x0 = row[512 + 2 * tid], x1 = row[512 + 2 * tid + 1];
      float c  = rdv(cosb, (size_t)s * 32 + tid, f32in);
      float sn = rdv(sinb, (size_t)s * 32 + tid, f32in);
      kpe[s * 64 + 2 * tid]     = __float2bfloat16(x0 * c - x1 * sn);
      kpe[s * 64 + 2 * tid + 1] = __float2bfloat16(x0 * sn + x1 * c);
    }
  }
}

// ------ merged rope_q (b<2048) + build_vt (b>=2048, 512 blocks) -------------
__global__ __launch_bounds__(256) void rope_vt_merged(
    bf16* __restrict__ q, const void* __restrict__ cosb,
    const void* __restrict__ sinb, const bf16* __restrict__ kvb,
    bf16* __restrict__ Vt, const int* __restrict__ flagp)
{
  const int b = blockIdx.x, tid = threadIdx.x;
  __shared__ __align__(16) bf16 tile[64][136];
  if (b < 2048) {
    const int f32in = flagp[0];
    const int s = b;
#pragma unroll
    for (int it = 0; it < 2; it++) {
      int p = tid + it * 256;
      int hh = p >> 5, jj = p & 31;
      bf16* src = q + (size_t)s * 3072 + hh * 192 + 128 + 2 * jj;
      float x0 = __bfloat162float(src[0]);
      float x1 = __bfloat162float(src[1]);
      float c  = rdv(cosb, (size_t)s * 32 + jj, f32in);
      float sn = rdv(sinb, (size_t)s * 32 + jj, f32in);
      src[0] = __float2bfloat16(x0 * c - x1 * sn);
      src[1] = __float2bfloat16(x0 * sn + x1 * c);
    }
  } else {
    const int hb = b - 2048;                 // 0..511
    const int h = hb & 15;
    const int t0 = (hb >> 4) * 64;
#pragma unroll
    for (int i = 0; i < 4; i++) {
      int chunk = tid + i * 256;
      int row = chunk >> 4;
      int c8 = (chunk & 15) * 8;
      *(int4*)&tile[row][c8] =
          *(const int4*)(kvb + (size_t)(t0 + row) * 4096 + h * 256 + 128 + c8);
    }
    __syncthreads();
#pragma unroll
    for (int i = 0; i < 32; i++) {
      int idx = tid + i * 256;
      int d = idx >> 6;
      int t = idx & 63;
      Vt[((size_t)h * 128 + d) * 2048 + t0 + t] = tile[t][d];
    }
  }
}

// ---------------- flash attention (round-7 exact, known good) ----------------
__global__ __launch_bounds__(256) void attn_kernel(
    const bf16* __restrict__ Q, const bf16* __restrict__ kvb,
    const bf16* __restrict__ kpe, const bf16* __restrict__ Vt,
    bf16* __restrict__ Out)
{
  __shared__ __align__(16) bf16 Ks[64 * 200];
  __shared__ __align__(16) bf16 Vs[128 * 72];
  __shared__ __align__(16) bf16 plds[4][16 * 68];
  const int b = blockIdx.x;
  const int h = b & 15;
  const int tt = (b >> 4) & 15;
  const int q0 = ((b >> 8) ? (31 - tt) : tt) * 64;
  const int tid = threadIdx.x;
  const int wave = tid >> 6;
  const int lane = tid & 63;
  const int grp = lane >> 4, l16 = lane & 15;
  const int qrt = q0 + wave * 16;
  const bf16* Qbase = Q + (size_t)(qrt + l16) * 3072 + h * 192;
  short8x qf[6];
#pragma unroll
  for (int c = 0; c < 6; c++)
    qf[c] = *(const short8x*)(Qbase + c * 32 + grp * 8);
  float m_run[4], l_run[4];
  float4x o_acc[8] = {};
#pragma unroll
  for (int r = 0; r < 4; r++) { m_run[r] = -__builtin_inff(); l_run[r] = 0.f; }
  bf16* pl = &plds[wave][0];
  for (int t0 = 0; t0 <= q0; t0 += 64) {
#pragma unroll
    for (int i = 0; i < 4; i++) {
      int ch = tid + i * 256;
      int row = ch >> 4, c = ch & 15;
      *(int4*)&Ks[row * 200 + c * 8] =
          *(const int4*)(kvb + (size_t)(t0 + row) * 4096 + h * 256 + c * 8);
    }
#pragma unroll
    for (int i = 0; i < 2; i++) {
      int ch = tid + i * 256;
      int row = ch >> 3, c = ch & 7;
      *(int4*)&Ks[row * 200 + 128 + c * 8] =
          *(const int4*)(kpe + (size_t)(t0 + row) * 64 + c * 8);
    }
#pragma unroll
    for (int i = 0; i < 4; i++) {
      int ch = tid + i * 256;
      int row = ch >> 3, c = ch & 7;
      *(int4*)&Vs[row * 72 + c * 8] =
          *(const int4*)(Vt + ((size_t)h * 128 + row) * 2048 + t0 + c * 8);
    }
    __syncthreads();
    float4x sacc[4] = {};
#pragma unroll
    for (int n = 0; n < 4; n++) {
      const bf16* Kb = &Ks[(n * 16 + l16) * 200 + grp * 8];
#pragma unroll
      for (int c = 0; c < 6; c++) {
        short8x kf = *(const short8x*)(Kb + c * 32);
        sacc[n] = __builtin_amdgcn_mfma_f32_16x16x32_bf16(qf[c], kf, sacc[n], 0, 0, 0);
      }
    }
    float pv[4][4], alpha[4];
#pragma unroll
    for (int r = 0; r < 4; r++) {
      const int s_row = qrt + grp * 4 + r;
      float p0[4];
      float mx = -__builtin_inff();
#pragma unroll
      for (int n = 0; n < 4; n++) {
        int t = t0 + n * 16 + l16;
        float v = sacc[n][r] * SCALE_F;
        v = (t > s_row) ? -1.0e9f : v;
        p0[n] = v;
        mx = fmaxf(mx, v);
      }
      mx = fmaxf(mx, __shfl_xor(mx, 1));
      mx = fmaxf(mx, __shfl_xor(mx, 2));
      mx = fmaxf(mx, __shfl_xor(mx, 4));
      mx = fmaxf(mx, __shfl_xor(mx, 8));
      float m_new = fmaxf(m_run[r], mx);
      float a = __expf(m_run[r] - m_new);
      m_run[r] = m_new;
      float sum = 0.f;
#pragma unroll
      for (int n = 0; n < 4; n++) {
        float e = __expf(p0[n] - m_new);
        pv[n][r] = e;
        sum += e;
      }
      sum += __shfl_xor(sum, 1);
      sum += __shfl_xor(sum, 2);
      sum += __shfl_xor(sum, 4);
      sum += __shfl_xor(sum, 8);
      l_run[r] = l_run[r] * a + sum;
      alpha[r] = a;
    }
#pragma unroll
    for (int n = 0; n < 8; n++)
#pragma unroll
      for (int r = 0; r < 4; r++)
        o_acc[n][r] *= alpha[r];
#pragma unroll
    for (int n = 0; n < 4; n++)
#pragma unroll
      for (int r = 0; r < 4; r++)
        pl[(grp * 4 + r) * 68 + n * 16 + l16] = __float2bfloat16(pv[n][r]);
#pragma unroll
    for (int c = 0; c < 2; c++) {
      union { short4x h4[2]; short8x v8; } pk;
      const bf16* pp = pl + l16 * 68 + c * 32 + grp * 8;
      pk.h4[0] = *(const short4x*)(pp);
      pk.h4[1] = *(const short4x*)(pp + 4);
#pragma unroll
      for (int n = 0; n < 8; n++) {
        short8x vf = *(const short8x*)&Vs[(size_t)(n * 16 + l16) * 72 + c * 32 + grp * 8];
        o_acc[n] = __builtin_amdgcn_mfma_f32_16x16x32_bf16(pk.v8, vf, o_acc[n], 0, 0, 0);
      }
    }
    __syncthreads();
  }
  float inv[4];
#pragma unroll
  for (int r = 0; r < 4; r++) inv[r] = 1.0f / l_run[r];
#pragma unroll
  for (int n = 0; n < 8; n++)
#pragma unroll
    for (int r = 0; r < 4; r++) {
      int s_row = qrt + grp * 4 + r;
      Out[(size_t)s_row * 2048 + h * 128 + n * 16 + l16] =
          __float2bfloat16(o_acc[n][r] * inv[r]);
    }
}

extern "C" void kernel_launch(void* const* d_in, const int* in_sizes, int n_in,
                              void* d_out, int out_size, void* d_ws, size_t ws_size,
                              hipStream_t stream) {
  const void* x        = d_in[0];
  const void* fcos     = d_in[2];
  const void* fsin     = d_in[3];
  const void* wq_a_w   = d_in[5];
  const void* wq_a_b   = d_in[6];
  const void* q_norm_w = d_in[7];
  const void* wq_b_w   = d_in[8];
  const void* wq_b_b   = d_in[9];
  const void* wkv_a_w  = d_in[10];
  const void* wkv_a_b  = d_in[11];
  const void* kv_norm_w= d_in[12];
  const void* wkv_b_w  = d_in[13];
  const void* wkv_b_b  = d_in[14];
  const void* wo_w     = d_in[15];
  const void* wo_b     = d_in[16];

  const size_t KB = 1024, MB = 1024 * 1024;
  if (ws_size < 46 * MB) {   // diagnostic: absmax ~1000 => ws too small
    sentinel_kernel<<<(out_size + 255) / 256, 256, 0, stream>>>((bf16*)d_out, out_size);
    return;
  }
  char* ws = (char*)d_ws;
  // Region plan, peak 44.5 MB (< proven-safe 45.25). Time-disjoint overlays:
  //   persistent:  kpe[0,0.25) flag@0.25M  qbuf[0.5,12.5) kvb[12.5,28.5)
  //                Vt[28.5,36.5) attnout[36.5,44.5)
  //   transients:  q_a[28.5,32.5) kv_a[32.5,37)  (dead after norms; Vt/attnout
  //                written later)   qn[37,39) kvn[39,41) (dead after gemmB;
  //                inside attnout, which is written by attn afterwards)
  bf16*  kpe    = (bf16*)(ws);
  int*   flag   = (int*)(ws + 256 * KB);
  bf16*  qbuf   = (bf16*)(ws + 512 * KB);
  bf16*  kvb    = (bf16*)(ws + 12 * MB + 512 * KB);
  bf16*  Vt     = (bf16*)(ws + 28 * MB + 512 * KB);
  bf16*  attnout= (bf16*)(ws + 36 * MB + 512 * KB);
  float* q_a    = (float*)(ws + 28 * MB + 512 * KB);
  float* kv_a   = (float*)(ws + 32 * MB + 512 * KB);
  bf16*  qn     = (bf16*)(ws + 37 * MB);
  bf16*  kvn    = (bf16*)(ws + 39 * MB);

  dim3 blk(256);
  detect_dtype<<<1, blk, 0, stream>>>((const unsigned short*)x, flag);
  // q_a and kv_a projections fused into one dispatch (544 active blocks)
  gemmA_dual<<<dim3(32, 9, 2), blk, 0, stream>>>(
      x, wq_a_w, wkv_a_w, wq_a_b, wkv_a_b, q_a, kv_a, flag);
  // both norms fused (4096 blocks)
  norms_merged<<<4096, blk, 0, stream>>>(
      q_a, kv_a, q_norm_w, kv_norm_w, fcos, fsin, qn, kvn, kpe, flag);
  // q_b and kv_b fused (896 active blocks, ~3.5/CU)
  gemmB_dual<<<dim3(16, 32, 2), blk, 0, stream>>>(
      qn, kvn, wq_b_w, wkv_b_w, wq_b_b, wkv_b_b, qbuf, kvb, flag);
  // rope on q (in place) + V transpose fused (2560 blocks)
  rope_vt_merged<<<2560, blk, 0, stream>>>(qbuf, fcos, fsin, kvb, Vt, flag);
  // attention (balanced flat-grid swizzle) + output projection
  attn_kernel<<<dim3(512), blk, 0, stream>>>(qbuf, kvb, kpe, Vt, attnout);
  gemm128<2, false><<<dim3(16, 16), blk, 0, stream>>>(
      attnout, wo_w, wo_b, d_out, 2048, 2048, 2048, flag);
}

// Round 9
// 345.198 us; speedup vs baseline: 2.3439x; 1.1134x over previous
//
#include <hip/hip_runtime.h>
#include <hip/hip_bf16.h>

typedef __attribute__((ext_vector_type(8))) short short8x;  // 8 bf16 = 4 VGPR
typedef __attribute__((ext_vector_type(4))) short short4x;  // 8B
typedef __attribute__((ext_vector_type(4))) float float4x;  // MFMA C/D
typedef __hip_bfloat16 bf16;

#define EPS_F 1.1920929e-07f
#define SCALE_F 0.07216878364870323f   // 192^-0.5

// flag semantics: 0 = primary inputs are bf16, 1 = primary inputs are fp32
__device__ inline float rdv(const void* p, size_t i, int f32) {
  return f32 ? ((const float*)p)[i] : __bfloat162float(((const bf16*)p)[i]);
}

__device__ inline int4 pack8(const float* s) {   // 8 fp32 -> 8 bf16 (RNE)
  unsigned short h[8];
#pragma unroll
  for (int t = 0; t < 8; t++) {
    bf16 b = __float2bfloat16(s[t]);
    __builtin_memcpy(&h[t], &b, 2);
  }
  int4 r;
  r.x = (int)((unsigned)h[0] | ((unsigned)h[1] << 16));
  r.y = (int)((unsigned)h[2] | ((unsigned)h[3] << 16));
  r.z = (int)((unsigned)h[4] | ((unsigned)h[5] << 16));
  r.w = (int)((unsigned)h[6] | ((unsigned)h[7] << 16));
  return r;
}

// async global->LDS, 16B per lane; LDS dest = wave-uniform base + lane*16
typedef __attribute__((address_space(1))) const unsigned int gu32;
typedef __attribute__((address_space(3))) unsigned int lu32;
__device__ __forceinline__ void gload16(const void* g, void* l) {
  __builtin_amdgcn_global_load_lds((gu32*)g, (lu32*)l, 16, 0, 0);
}

// -------- dtype detector --------
__global__ __launch_bounds__(256) void detect_dtype(const unsigned short* __restrict__ x,
                                                    int* __restrict__ flag) {
  int tid = threadIdx.x;
  int cnt = 0;
#pragma unroll
  for (int i = 0; i < 4; i++) {
    unsigned short u = x[tid * 4 + i];
    int e = (u >> 7) & 0xFF;
    cnt += (e >= 118 && e <= 130) ? 1 : 0;
  }
#pragma unroll
  for (int off = 1; off < 64; off <<= 1) cnt += __shfl_xor(cnt, off);
  __shared__ int red[4];
  if ((tid & 63) == 0) red[tid >> 6] = cnt;
  __syncthreads();
  if (tid == 0) flag[0] = ((red[0] + red[1] + red[2] + red[3]) > 768) ? 0 : 1;
}

__global__ __launch_bounds__(256) void sentinel_kernel(bf16* out, int n) {
  int i = blockIdx.x * 256 + threadIdx.x;
  if (i < n) out[i] = __float2bfloat16(1000.0f);
}

// ---------------- GEMM 128x128 body (round-7 logic + kbeg/kend/addbias) -----
template<int OMODE, bool A_DYN>
__device__ __forceinline__ void gemm128_body(
    const void* __restrict__ A, const void* __restrict__ W,
    const void* __restrict__ bias, void* __restrict__ Cout,
    int M, int N, int K, int f32in, int bx, int by,
    int kbeg, int kend, int addbias)
{
  __shared__ int4 As4[128 * 4];
  __shared__ int4 Bs4[128 * 4];
  const int tid = threadIdx.x, lane = tid & 63, wave = tid >> 6;
  const int grp = lane >> 4, l16 = lane & 15;
  const int m0 = bx * 128, n0 = by * 128;
  const int wm = (wave & 1) * 64, wn = (wave >> 1) * 64;
  float4x acc[4][4] = {};
  for (int k0 = kbeg; k0 < kend; k0 += 32) {
    if (!f32in) {
#pragma unroll
      for (int j = 0; j < 2; j++) {
        int row = wave * 32 + j * 16 + (lane >> 2);
        int cs = (lane & 3) ^ ((row >> 1) & 3);
        gload16((const bf16*)A + (size_t)(m0 + row) * K + k0 + cs * 8,
                &As4[(wave * 32 + j * 16) * 4]);
        gload16((const bf16*)W + (size_t)(n0 + row) * K + k0 + cs * 8,
                &Bs4[(wave * 32 + j * 16) * 4]);
      }
    } else {
#pragma unroll
      for (int i = 0; i < 2; i++) {
        int ch = tid + i * 256;
        int row = ch >> 2, c = ch & 3;
        int cs = c ^ ((row >> 1) & 3);
        size_t aoff = (size_t)(m0 + row) * K + k0 + cs * 8;
        size_t boff = (size_t)(n0 + row) * K + k0 + cs * 8;
        As4[row * 4 + c] = A_DYN ? pack8((const float*)A + aoff)
                                 : *(const int4*)((const bf16*)A + aoff);
        Bs4[row * 4 + c] = pack8((const float*)W + boff);
      }
    }
    __syncthreads();
    short8x af[4], bfr[4];
#pragma unroll
    for (int i = 0; i < 4; i++) {
      int ra = wm + i * 16 + l16;
      int rb = wn + i * 16 + l16;
      af[i]  = *(const short8x*)&As4[ra * 4 + (grp ^ ((ra >> 1) & 3))];
      bfr[i] = *(const short8x*)&Bs4[rb * 4 + (grp ^ ((rb >> 1) & 3))];
    }
#pragma unroll
    for (int i = 0; i < 4; i++)
#pragma unroll
      for (int j = 0; j < 4; j++)
        acc[i][j] = __builtin_amdgcn_mfma_f32_16x16x32_bf16(af[i], bfr[j], acc[i][j], 0, 0, 0);
    __syncthreads();
  }
#pragma unroll
  for (int j = 0; j < 4; j++) {
    int gn = n0 + wn + j * 16 + l16;
    float bv = addbias ? rdv(bias, gn, f32in) : 0.0f;
#pragma unroll
    for (int i = 0; i < 4; i++) {
      int gm0 = m0 + wm + i * 16 + grp * 4;
#pragma unroll
      for (int r = 0; r < 4; r++) {
        float v = acc[i][j][r] + bv;
        size_t idx = (size_t)(gm0 + r) * N + gn;
        if (OMODE == 0)      ((float*)Cout)[idx] = v;
        else if (OMODE == 1) ((bf16*)Cout)[idx] = __float2bfloat16(v);
        else {
          if (f32in) ((float*)Cout)[idx] = v;
          else       ((bf16*)Cout)[idx] = __float2bfloat16(v);
        }
      }
    }
  }
}

// q_b and kv_b in one dispatch: z=0 -> (qn,wq_b)->qbuf N=3072 (24 tiles);
// z=1 -> (kvn,wkv_b)->kvb N=4096 (32 tiles). Grid (16,32,2).
__global__ __launch_bounds__(256) void gemmB_dual(
    const void* __restrict__ A0, const void* __restrict__ A1,
    const void* __restrict__ W0, const void* __restrict__ W1,
    const void* __restrict__ b0, const void* __restrict__ b1,
    void* __restrict__ C0, void* __restrict__ C1,
    const int* __restrict__ flagp)
{
  const int z = blockIdx.z;
  if (z == 0 && blockIdx.y >= 24) return;
  const void* A = z ? A1 : A0;
  const void* W = z ? W1 : W0;
  const void* bias = z ? b1 : b0;
  void* C = z ? C1 : C0;
  const int N = z ? 4096 : 3072;
  gemm128_body<1, false>(A, W, bias, C, 2048, N, 512, flagp[0],
                         blockIdx.x, blockIdx.y, 0, 512, 1);
}

// wo split-K=2: z in {0,1} covers K-half, fp32 partials, bias in z==0.
// Grid (16,16,2) = 512 blocks (2/CU).
__global__ __launch_bounds__(256) void gemmWo_sk(
    const void* __restrict__ A, const void* __restrict__ W,
    const void* __restrict__ bias, float* __restrict__ part,
    const int* __restrict__ flagp)
{
  const int z = blockIdx.z;
  gemm128_body<0, false>(A, W, bias, part + (size_t)z * 2048 * 2048,
                         2048, 2048, 2048, flagp[0],
                         blockIdx.x, blockIdx.y, z * 1024, z * 1024 + 1024, z == 0);
}

// reduce: out = part0 + part1 (bias already in part0); out dtype per flag
__global__ __launch_bounds__(256) void reduce_out(
    const float* __restrict__ p0, const float* __restrict__ p1,
    void* __restrict__ out, const int* __restrict__ flagp)
{
  const int f32in = flagp[0];
  size_t i = ((size_t)blockIdx.x * 256 + threadIdx.x) * 4;
  float4 a = *(const float4*)(p0 + i);
  float4 b = *(const float4*)(p1 + i);
  a.x += b.x; a.y += b.y; a.z += b.z; a.w += b.w;
  if (f32in) {
    *(float4*)((float*)out + i) = a;
  } else {
    unsigned short h[4];
    bf16 t0 = __float2bfloat16(a.x); __builtin_memcpy(&h[0], &t0, 2);
    bf16 t1 = __float2bfloat16(a.y); __builtin_memcpy(&h[1], &t1, 2);
    bf16 t2 = __float2bfloat16(a.z); __builtin_memcpy(&h[2], &t2, 2);
    bf16 t3 = __float2bfloat16(a.w); __builtin_memcpy(&h[3], &t3, 2);
    int2 v;
    v.x = (int)((unsigned)h[0] | ((unsigned)h[1] << 16));
    v.y = (int)((unsigned)h[2] | ((unsigned)h[3] << 16));
    *(int2*)((bf16*)out + i) = v;
  }
}

// ---------------- GEMM 64x64 body (round-7 logic + kbeg/kend/addbias) -------
template<int OMODE, bool A_DYN>
__device__ __forceinline__ void gemm64_body(
    const void* __restrict__ A, const void* __restrict__ W,
    const void* __restrict__ bias, void* __restrict__ Cout,
    int M, int N, int K, int f32in, int bx, int by,
    int kbeg, int kend, int addbias)
{
  __shared__ int4 As4[64 * 4];
  __shared__ int4 Bs4[64 * 4];
  const int tid = threadIdx.x, lane = tid & 63, wave = tid >> 6;
  const int grp = lane >> 4, l16 = lane & 15;
  const int m0 = bx * 64, n0 = by * 64;
  const int wm = (wave & 1) * 32, wn = (wave >> 1) * 32;
  float4x acc[2][2] = {};
  for (int k0 = kbeg; k0 < kend; k0 += 32) {
    if (!f32in) {
      int row = wave * 16 + (lane >> 2);
      int cs = (lane & 3) ^ ((row >> 1) & 3);
      gload16((const bf16*)A + (size_t)(m0 + row) * K + k0 + cs * 8,
              &As4[wave * 16 * 4]);
      gload16((const bf16*)W + (size_t)(n0 + row) * K + k0 + cs * 8,
              &Bs4[wave * 16 * 4]);
    } else {
      int row = tid >> 2, c = tid & 3;
      int cs = c ^ ((row >> 1) & 3);
      size_t aoff = (size_t)(m0 + row) * K + k0 + cs * 8;
      size_t boff = (size_t)(n0 + row) * K + k0 + cs * 8;
      As4[row * 4 + c] = A_DYN ? pack8((const float*)A + aoff)
                               : *(const int4*)((const bf16*)A + aoff);
      Bs4[row * 4 + c] = pack8((const float*)W + boff);
    }
    __syncthreads();
    short8x af[2], bfr[2];
#pragma unroll
    for (int i = 0; i < 2; i++) {
      int ra = wm + i * 16 + l16;
      int rb = wn + i * 16 + l16;
      af[i]  = *(const short8x*)&As4[ra * 4 + (grp ^ ((ra >> 1) & 3))];
      bfr[i] = *(const short8x*)&Bs4[rb * 4 + (grp ^ ((rb >> 1) & 3))];
    }
#pragma unroll
    for (int i = 0; i < 2; i++)
#pragma unroll
      for (int j = 0; j < 2; j++)
        acc[i][j] = __builtin_amdgcn_mfma_f32_16x16x32_bf16(af[i], bfr[j], acc[i][j], 0, 0, 0);
    __syncthreads();
  }
#pragma unroll
  for (int j = 0; j < 2; j++) {
    int gn = n0 + wn + j * 16 + l16;
    float bv = addbias ? rdv(bias, gn, f32in) : 0.0f;
#pragma unroll
    for (int i = 0; i < 2; i++) {
      int gm0 = m0 + wm + i * 16 + grp * 4;
#pragma unroll
      for (int r = 0; r < 4; r++) {
        float v = acc[i][j][r] + bv;
        size_t idx = (size_t)(gm0 + r) * N + gn;
        if (OMODE == 0)      ((float*)Cout)[idx] = v;
        else if (OMODE == 1) ((bf16*)Cout)[idx] = __float2bfloat16(v);
        else {
          if (f32in) ((float*)Cout)[idx] = v;
          else       ((bf16*)Cout)[idx] = __float2bfloat16(v);
        }
      }
    }
  }
}

// q_a/kv_a projections, split-K=2, fused: grid (32,9,4);
// z = (mat<<1)|khalf; mat 0 -> q (N=512, skip y==8), mat 1 -> kv (N=576).
// fp32 partials C + khalf*M*N; bias in khalf==0.
__global__ __launch_bounds__(256) void gemmA_sk(
    const void* __restrict__ A,
    const void* __restrict__ W0, const void* __restrict__ W1,
    const void* __restrict__ b0, const void* __restrict__ b1,
    float* __restrict__ C0, float* __restrict__ C1,
    const int* __restrict__ flagp)
{
  const int z = blockIdx.z;
  const int mat = z >> 1, kh = z & 1;
  const int N = mat ? 576 : 512;
  if (blockIdx.y * 64 >= N) return;
  const void* W = mat ? W1 : W0;
  const void* bias = mat ? b1 : b0;
  float* C = (mat ? C1 : C0) + (size_t)kh * 2048 * N;
  gemm64_body<0, true>(A, W, bias, C, 2048, N, 2048, flagp[0],
                       blockIdx.x, blockIdx.y,
                       kh * 1024, kh * 1024 + 1024, kh == 0);
}

// ------ merged norms w/ fused split-K reduce: b<2048 -> q; else kv ----------
__global__ __launch_bounds__(256) void norms_merged(
    const float* __restrict__ q_a0, const float* __restrict__ q_a1,
    const float* __restrict__ kv_a0, const float* __restrict__ kv_a1,
    const void* __restrict__ qw, const void* __restrict__ kvw,
    const void* __restrict__ cosb, const void* __restrict__ sinb,
    bf16* __restrict__ qn, bf16* __restrict__ kvn, bf16* __restrict__ kpe,
    const int* __restrict__ flagp)
{
  const int f32in = flagp[0];
  const int b = blockIdx.x, tid = threadIdx.x;
  __shared__ float red[4];
  if (b < 2048) {
    const int s = b;
    size_t base = (size_t)s * 512;
    float v0 = q_a0[base + tid] + q_a1[base + tid];
    float v1 = q_a0[base + tid + 256] + q_a1[base + tid + 256];
    float ss = v0 * v0 + v1 * v1;
#pragma unroll
    for (int off = 1; off < 64; off <<= 1) ss += __shfl_xor(ss, off);
    if ((tid & 63) == 0) red[tid >> 6] = ss;
    __syncthreads();
    float tot = red[0] + red[1] + red[2] + red[3];
    float scale = rsqrtf(tot * (1.0f / 512.0f) + EPS_F);
    qn[base + tid]       = __float2bfloat16(v0 * scale * rdv(qw, tid, f32in));
    qn[base + tid + 256] = __float2bfloat16(v1 * scale * rdv(qw, tid + 256, f32in));
  } else {
    const int s = b - 2048;
    size_t base = (size_t)s * 576;
    float v0 = kv_a0[base + tid] + kv_a1[base + tid];
    float v1 = kv_a0[base + tid + 256] + kv_a1[base + tid + 256];
    float ss = v0 * v0 + v1 * v1;
#pragma unroll
    for (int off = 1; off < 64; off <<= 1) ss += __shfl_xor(ss, off);
    if ((tid & 63) == 0) red[tid >> 6] = ss;
    __syncthreads();
    float tot = red[0] + red[1] + red[2] + red[3];
    float scale = rsqrtf(tot * (1.0f / 512.0f) + EPS_F);
    kvn[(size_t)s * 512 + tid]       = __float2bfloat16(v0 * scale * rdv(kvw, tid, f32in));
    kvn[(size_t)s * 512 + tid + 256] = __float2bfloat16(v1 * scale * rdv(kvw, tid + 256, f32in));
    if (tid < 32) {
      float x0 = kv_a0[base + 512 + 2 * tid] + kv_a1[base + 512 + 2 * tid];
      float x1 = kv_a0[base + 512 + 2 * tid + 1] + kv_a1[base + 512 + 2 * tid + 1];
      float c  = rdv(cosb, (size_t)s * 32 + tid, f32in);
      float sn = rdv(sinb, (size_t)s * 32 + tid, f32in);
      kpe[s * 64 + 2 * tid]     = __float2bfloat16(x0 * c - x1 * sn);
      kpe[s * 64 + 2 * tid + 1] = __float2bfloat16(x0 * sn + x1 * c);
    }
  }
}

// ------ merged rope_q (b<2048) + build_vt (b>=2048, 512 blocks) -------------
__global__ __launch_bounds__(256) void rope_vt_merged(
    bf16* __restrict__ q, const void* __restrict__ cosb,
    const void* __restrict__ sinb, const bf16* __restrict__ kvb,
    bf16* __restrict__ Vt, const int* __restrict__ flagp)
{
  const int b = blockIdx.x, tid = threadIdx.x;
  __shared__ __align__(16) bf16 tile[64][136];
  if (b < 2048) {
    const int f32in = flagp[0];
    const int s = b;
#pragma unroll
    for (int it = 0; it < 2; it++) {
      int p = tid + it * 256;
      int hh = p >> 5, jj = p & 31;
      bf16* src = q + (size_t)s * 3072 + hh * 192 + 128 + 2 * jj;
      float x0 = __bfloat162float(src[0]);
      float x1 = __bfloat162float(src[1]);
      float c  = rdv(cosb, (size_t)s * 32 + jj, f32in);
      float sn = rdv(sinb, (size_t)s * 32 + jj, f32in);
      src[0] = __float2bfloat16(x0 * c - x1 * sn);
      src[1] = __float2bfloat16(x0 * sn + x1 * c);
    }
  } else {
    const int hb = b - 2048;                 // 0..511
    const int h = hb & 15;
    const int t0 = (hb >> 4) * 64;
#pragma unroll
    for (int i = 0; i < 4; i++) {
      int chunk = tid + i * 256;
      int row = chunk >> 4;
      int c8 = (chunk & 15) * 8;
      *(int4*)&tile[row][c8] =
          *(const int4*)(kvb + (size_t)(t0 + row) * 4096 + h * 256 + 128 + c8);
    }
    __syncthreads();
#pragma unroll
    for (int i = 0; i < 32; i++) {
      int idx = tid + i * 256;
      int d = idx >> 6;
      int t = idx & 63;
      Vt[((size_t)h * 128 + d) * 2048 + t0 + t] = tile[t][d];
    }
  }
}

// ---------------- flash attention (round-7 exact, known good) ----------------
__global__ __launch_bounds__(256) void attn_kernel(
    const bf16* __restrict__ Q, const bf16* __restrict__ kvb,
    const bf16* __restrict__ kpe, const bf16* __restrict__ Vt,
    bf16* __restrict__ Out)
{
  __shared__ __align__(16) bf16 Ks[64 * 200];
  __shared__ __align__(16) bf16 Vs[128 * 72];
  __shared__ __align__(16) bf16 plds[4][16 * 68];
  const int b = blockIdx.x;
  const int h = b & 15;
  const int tt = (b >> 4) & 15;
  const int q0 = ((b >> 8) ? (31 - tt) : tt) * 64;
  const int tid = threadIdx.x;
  const int wave = tid >> 6;
  const int lane = tid & 63;
  const int grp = lane >> 4, l16 = lane & 15;
  const int qrt = q0 + wave * 16;
  const bf16* Qbase = Q + (size_t)(qrt + l16) * 3072 + h * 192;
  short8x qf[6];
#pragma unroll
  for (int c = 0; c < 6; c++)
    qf[c] = *(const short8x*)(Qbase + c * 32 + grp * 8);
  float m_run[4], l_run[4];
  float4x o_acc[8] = {};
#pragma unroll
  for (int r = 0; r < 4; r++) { m_run[r] = -__builtin_inff(); l_run[r] = 0.f; }
  bf16* pl = &plds[wave][0];
  for (int t0 = 0; t0 <= q0; t0 += 64) {
#pragma unroll
    for (int i = 0; i < 4; i++) {
      int ch = tid + i * 256;
      int row = ch >> 4, c = ch & 15;
      *(int4*)&Ks[row * 200 + c * 8] =
          *(const int4*)(kvb + (size_t)(t0 + row) * 4096 + h * 256 + c * 8);
    }
#pragma unroll
    for (int i = 0; i < 2; i++) {
      int ch = tid + i * 256;
      int row = ch >> 3, c = ch & 7;
      *(int4*)&Ks[row * 200 + 128 + c * 8] =
          *(const int4*)(kpe + (size_t)(t0 + row) * 64 + c * 8);
    }
#pragma unroll
    for (int i = 0; i < 4; i++) {
      int ch = tid + i * 256;
      int row = ch >> 3, c = ch & 7;
      *(int4*)&Vs[row * 72 + c * 8] =
          *(const int4*)(Vt + ((size_t)h * 128 + row) * 2048 + t0 + c * 8);
    }
    __syncthreads();
    float4x sacc[4] = {};
#pragma unroll
    for (int n = 0; n < 4; n++) {
      const bf16* Kb = &Ks[(n * 16 + l16) * 200 + grp * 8];
#pragma unroll
      for (int c = 0; c < 6; c++) {
        short8x kf = *(const short8x*)(Kb + c * 32);
        sacc[n] = __builtin_amdgcn_mfma_f32_16x16x32_bf16(qf[c], kf, sacc[n], 0, 0, 0);
      }
    }
    float pv[4][4], alpha[4];
#pragma unroll
    for (int r = 0; r < 4; r++) {
      const int s_row = qrt + grp * 4 + r;
      float p0[4];
      float mx = -__builtin_inff();
#pragma unroll
      for (int n = 0; n < 4; n++) {
        int t = t0 + n * 16 + l16;
        float v = sacc[n][r] * SCALE_F;
        v = (t > s_row) ? -1.0e9f : v;
        p0[n] = v;
        mx = fmaxf(mx, v);
      }
      mx = fmaxf(mx, __shfl_xor(mx, 1));
      mx = fmaxf(mx, __shfl_xor(mx, 2));
      mx = fmaxf(mx, __shfl_xor(mx, 4));
      mx = fmaxf(mx, __shfl_xor(mx, 8));
      float m_new = fmaxf(m_run[r], mx);
      float a = __expf(m_run[r] - m_new);
      m_run[r] = m_new;
      float sum = 0.f;
#pragma unroll
      for (int n = 0; n < 4; n++) {
        float e = __expf(p0[n] - m_new);
        pv[n][r] = e;
        sum += e;
      }
      sum += __shfl_xor(sum, 1);
      sum += __shfl_xor(sum, 2);
      sum += __shfl_xor(sum, 4);
      sum += __shfl_xor(sum, 8);
      l_run[r] = l_run[r] * a + sum;
      alpha[r] = a;
    }
#pragma unroll
    for (int n = 0; n < 8; n++)
#pragma unroll
      for (int r = 0; r < 4; r++)
        o_acc[n][r] *= alpha[r];
#pragma unroll
    for (int n = 0; n < 4; n++)
#pragma unroll
      for (int r = 0; r < 4; r++)
        pl[(grp * 4 + r) * 68 + n * 16 + l16] = __float2bfloat16(pv[n][r]);
#pragma unroll
    for (int c = 0; c < 2; c++) {
      union { short4x h4[2]; short8x v8; } pk;
      const bf16* pp = pl + l16 * 68 + c * 32 + grp * 8;
      pk.h4[0] = *(const short4x*)(pp);
      pk.h4[1] = *(const short4x*)(pp + 4);
#pragma unroll
      for (int n = 0; n < 8; n++) {
        short8x vf = *(const short8x*)&Vs[(size_t)(n * 16 + l16) * 72 + c * 32 + grp * 8];
        o_acc[n] = __builtin_amdgcn_mfma_f32_16x16x32_bf16(pk.v8, vf, o_acc[n], 0, 0, 0);
      }
    }
    __syncthreads();
  }
  float inv[4];
#pragma unroll
  for (int r = 0; r < 4; r++) inv[r] = 1.0f / l_run[r];
#pragma unroll
  for (int n = 0; n < 8; n++)
#pragma unroll
    for (int r = 0; r < 4; r++) {
      int s_row = qrt + grp * 4 + r;
      Out[(size_t)s_row * 2048 + h * 128 + n * 16 + l16] =
          __float2bfloat16(o_acc[n][r] * inv[r]);
    }
}

extern "C" void kernel_launch(void* const* d_in, const int* in_sizes, int n_in,
                              void* d_out, int out_size, void* d_ws, size_t ws_size,
                              hipStream_t stream) {
  const void* x        = d_in[0];
  const void* fcos     = d_in[2];
  const void* fsin     = d_in[3];
  const void* wq_a_w   = d_in[5];
  const void* wq_a_b   = d_in[6];
  const void* q_norm_w = d_in[7];
  const void* wq_b_w   = d_in[8];
  const void* wq_b_b   = d_in[9];
  const void* wkv_a_w  = d_in[10];
  const void* wkv_a_b  = d_in[11];
  const void* kv_norm_w= d_in[12];
  const void* wkv_b_w  = d_in[13];
  const void* wkv_b_b  = d_in[14];
  const void* wo_w     = d_in[15];
  const void* wo_b     = d_in[16];

  const size_t KB = 1024, MB = 1024 * 1024;
  if (ws_size < 46 * MB) {   // diagnostic: absmax ~1000 => ws too small
    sentinel_kernel<<<(out_size + 255) / 256, 256, 0, stream>>>((bf16*)d_out, out_size);
    return;
  }
  char* ws = (char*)d_ws;
  // Region plan, peak 44.5 MB. Persistent: kpe[0,0.25M) flag@0.25M
  //   qbuf[0.5,12.5) kvb[12.5,28.5) Vt[28.5,36.5) attnout[36.5,44.5).
  // Transients (time-disjoint with their hosts):
  //   kv_a0/1 [0.5,9.5)   in qbuf   (dead before gemmB writes qbuf)
  //   q_a0/1  [36.5,44.5) in attnout(dead before attn writes attnout)
  //   qn/kvn  [28.5,32.5) in Vt     (dead before rope_vt writes Vt)
  //   wpart   [0.5,32.5)  in qbuf+kvb+Vt (all dead after attn)
  bf16*  kpe    = (bf16*)(ws);
  int*   flag   = (int*)(ws + 256 * KB);
  bf16*  qbuf   = (bf16*)(ws + 512 * KB);
  bf16*  kvb    = (bf16*)(ws + 12 * MB + 512 * KB);
  bf16*  Vt     = (bf16*)(ws + 28 * MB + 512 * KB);
  bf16*  attnout= (bf16*)(ws + 36 * MB + 512 * KB);
  float* kv_a0  = (float*)(ws + 512 * KB);
  float* kv_a1  = (float*)(ws + 5 * MB);
  float* q_a0   = (float*)(ws + 36 * MB + 512 * KB);
  float* q_a1   = (float*)(ws + 40 * MB + 512 * KB);
  bf16*  qn     = (bf16*)(ws + 28 * MB + 512 * KB);
  bf16*  kvn    = (bf16*)(ws + 30 * MB + 512 * KB);
  float* wpart  = (float*)(ws + 512 * KB);

  dim3 blk(256);
  detect_dtype<<<1, blk, 0, stream>>>((const unsigned short*)x, flag);
  // q_a and kv_a projections, split-K=2, one dispatch (1088 active blocks)
  gemmA_sk<<<dim3(32, 9, 4), blk, 0, stream>>>(
      x, wq_a_w, wkv_a_w, wq_a_b, wkv_a_b, q_a0, kv_a0, flag);
  // both norms + split-K reduce fused (4096 blocks)
  norms_merged<<<4096, blk, 0, stream>>>(
      q_a0, q_a1, kv_a0, kv_a1, q_norm_w, kv_norm_w, fcos, fsin,
      qn, kvn, kpe, flag);
  // q_b and kv_b fused (896 active blocks, ~3.5/CU)
  gemmB_dual<<<dim3(16, 32, 2), blk, 0, stream>>>(
      qn, kvn, wq_b_w, wkv_b_w, wq_b_b, wkv_b_b, qbuf, kvb, flag);
  // rope on q (in place) + V transpose fused (2560 blocks)
  rope_vt_merged<<<2560, blk, 0, stream>>>(qbuf, fcos, fsin, kvb, Vt, flag);
  // attention (balanced flat-grid swizzle)
  attn_kernel<<<dim3(512), blk, 0, stream>>>(qbuf, kvb, kpe, Vt, attnout);
  // output projection split-K=2 (512 blocks) + reduce
  gemmWo_sk<<<dim3(16, 16, 2), blk, 0, stream>>>(attnout, wo_w, wo_b, wpart, flag);
  reduce_out<<<4096, blk, 0, stream>>>(wpart, wpart + (size_t)2048 * 2048, d_out, flag);
}